// Round 17
// baseline (596.993 us; speedup 1.0000x reference)
//
#include <hip/hip_runtime.h>
#include <hip/hip_bf16.h>

// Problem constants (fixed by the reference)
#define B_ 1024
#define L_ 32
#define M_ 128
#define N_ 4096
#define S_ 32
#define ROWS (B_ * L_)          // 32768 rows of length N_

typedef __attribute__((ext_vector_type(8))) short    short8_t;   // 8 bf16 (4 VGPR)
typedef __attribute__((ext_vector_type(8))) unsigned short ushort8_t;
typedef __attribute__((ext_vector_type(4))) float    f32x4;
typedef __attribute__((ext_vector_type(4))) unsigned int uint4_t;

__device__ __forceinline__ unsigned short f2bf(float x) {  // RNE bf16
    unsigned u = __float_as_uint(x);
    unsigned r = (u + 0x7FFFu + ((u >> 16) & 1u)) >> 16;
    return (unsigned short)r;
}
__device__ __forceinline__ float bf2f(unsigned short h) {
    return __uint_as_float((unsigned)h << 16);
}

// ---------------------------------------------------------------------------
// P0: PROLOGUE mega-kernel (block-range dispatch over independent jobs):
//   [0,2048)        zero LOW 8KB half of every y row (streaming writes)
//   [2048,10240)    prep_w: Wbf = bf16(We), cvec = b_d . We_n
//   [10240,26624)   prep_a: Abf = bf16(kin), layout [l][b][128]
//   [26624,26624+nT) transpose Wd -> WdT (only when WdT does NOT alias Wbf)
// ---------------------------------------------------------------------------
__global__ __launch_bounds__(256) void prologue(float* __restrict__ y,
                                                const float* __restrict__ We,
                                                const float* __restrict__ bd,
                                                unsigned short* __restrict__ Wbf,
                                                float* __restrict__ cvec,
                                                const float* __restrict__ kin,
                                                unsigned short* __restrict__ Abf,
                                                const float* __restrict__ Wd,
                                                float* __restrict__ WdT) {
    __shared__ float t[32][33];
    const int bid = blockIdx.x;
    const int tid = threadIdx.x;

    if (bid < 2048) {
        const float4 z = {0.f, 0.f, 0.f, 0.f};
        int idx = bid * 256 + tid;
        for (int i = idx; i < ROWS * 512; i += 2048 * 256) {
            int row = i >> 9, slot = i & 511;
            reinterpret_cast<float4*>(y + (size_t)row * N_)[slot] = z;
        }
    } else if (bid < 10240) {
        int wb = bid - 2048;
        int l = wb >> 8, nb = wb & 255;
        int nl = tid >> 4, tt = tid & 15;
        int n = nb * 16 + nl;
        const float* w = We + ((size_t)l * N_ + n) * M_ + tt * 8;
        const float* b = bd + l * M_ + tt * 8;
        float4 w0 = *(const float4*)(w), w1 = *(const float4*)(w + 4);
        float4 b0 = *(const float4*)(b), b1 = *(const float4*)(b + 4);
        ushort8_t o;
        o[0] = f2bf(w0.x); o[1] = f2bf(w0.y); o[2] = f2bf(w0.z); o[3] = f2bf(w0.w);
        o[4] = f2bf(w1.x); o[5] = f2bf(w1.y); o[6] = f2bf(w1.z); o[7] = f2bf(w1.w);
        *reinterpret_cast<ushort8_t*>(Wbf + ((size_t)l * N_ + n) * 128 + tt * 8) = o;
        float s = w0.x*b0.x + w0.y*b0.y + w0.z*b0.z + w0.w*b0.w
                + w1.x*b1.x + w1.y*b1.y + w1.z*b1.z + w1.w*b1.w;
        #pragma unroll
        for (int oo = 8; oo > 0; oo >>= 1) s += __shfl_xor(s, oo, 64);
        if (tt == 0) cvec[(size_t)l * N_ + n] = s;
    } else if (bid < 26624) {
        int g = (bid - 10240) * 256 + tid;        // over B*L*M
        int b = g >> 12, l = (g >> 7) & 31, m = g & 127;
        Abf[(((size_t)l * B_ + b) << 7) + m] = f2bf(kin[g]);
    } else {
        int tb = bid - 26624;
        int l  = tb >> 9;
        int rem = tb & 511;
        int n0 = (rem & 127) * 32, m0 = (rem >> 7) * 32;
        int tx = tid & 31, ty = tid >> 5;
        const float* src = Wd + (size_t)l * M_ * N_;
        for (int i = ty; i < 32; i += 8)
            t[i][tx] = src[(size_t)(m0 + i) * N_ + n0 + tx];
        __syncthreads();
        float* dst = WdT + (size_t)l * N_ * M_;
        for (int i = ty; i < 32; i += 8)
            dst[(size_t)(n0 + i) * M_ + m0 + tx] = t[tx][i];
    }
}

// ---------------------------------------------------------------------------
// K0: standalone transpose (fallback when WdT aliases Wbf)
// ---------------------------------------------------------------------------
__global__ __launch_bounds__(256) void transpose_wd(const float* __restrict__ Wd,
                                                    float* __restrict__ WdT) {
    __shared__ float t[32][33];
    int l = blockIdx.z;
    int n0 = blockIdx.x * 32, m0 = blockIdx.y * 32;
    int tx = threadIdx.x & 31, ty = threadIdx.x >> 5;
    const float* src = Wd + (size_t)l * M_ * N_;
    for (int i = ty; i < 32; i += 8)
        t[i][tx] = src[(size_t)(m0 + i) * N_ + n0 + tx];
    __syncthreads();
    float* dst = WdT + (size_t)l * N_ * M_;
    for (int i = ty; i < 32; i += 8)
        dst[(size_t)(n0 + i) * M_ + m0 + tx] = t[tx][i];
}

// ---------------------------------------------------------------------------
// K1: encoder approx GEMM via MFMA bf16, single term (K=128, 4 BK=32 steps).
// Epilogue: padded-LDS re-tile -> coalesced 16B stores to the HIGH half.
// ---------------------------------------------------------------------------
__device__ __forceinline__ int swz(int row) { return (row & 3) ^ ((row >> 2) & 3); }

#define CP 136   // C-tile row pitch in shorts

__global__ __launch_bounds__(256) void encoder_mfma(const unsigned short* __restrict__ Abf,
                                                    const unsigned short* __restrict__ Wbf,
                                                    const float* __restrict__ cvec,
                                                    unsigned short* __restrict__ y16) {
    const int l   = blockIdx.z;
    const int bn0 = blockIdx.x * 128;
    const int bm0 = blockIdx.y * 128;
    __shared__ __align__(16) unsigned short smem[128 * CP];   // 34.8KB
    unsigned short* As = smem;
    unsigned short* Bs = smem + 128 * 32;
    const int tid  = threadIdx.x;
    const int lane = tid & 63, wave = tid >> 6;
    const int wr = wave >> 1, wc = wave & 1;

    const unsigned short* Ab = Abf + (((size_t)l * B_ + bm0) << 7);
    const unsigned short* Wb = Wbf + (((size_t)l * N_ + bn0) << 7);

    auto stage = [&](int k0) {
        #pragma unroll
        for (int i = 0; i < 2; ++i) {
            int p   = i * 256 + tid;
            int row = p >> 2;
            int lc  = (p & 3) ^ swz(row);
            const unsigned short* g = Ab + ((size_t)row << 7) + k0 + lc * 8;
            unsigned dst = (unsigned)((i * 256 + (tid & ~63)) * 16);
            __builtin_amdgcn_global_load_lds(
                (const __attribute__((address_space(1))) void*)g,
                (__attribute__((address_space(3))) void*)((char*)As + dst), 16, 0, 0);
        }
        #pragma unroll
        for (int i = 0; i < 2; ++i) {
            int p   = i * 256 + tid;
            int row = p >> 2;
            int lc  = (p & 3) ^ swz(row);
            const unsigned short* g = Wb + ((size_t)row << 7) + k0 + lc * 8;
            unsigned dst = (unsigned)((i * 256 + (tid & ~63)) * 16);
            __builtin_amdgcn_global_load_lds(
                (const __attribute__((address_space(1))) void*)g,
                (__attribute__((address_space(3))) void*)((char*)Bs + dst), 16, 0, 0);
        }
    };

    f32x4 acc[4][4];
    #pragma unroll
    for (int i = 0; i < 4; ++i)
        #pragma unroll
        for (int j = 0; j < 4; ++j) acc[i][j] = (f32x4){0.f, 0.f, 0.f, 0.f};

    stage(0);
    __syncthreads();

    #pragma unroll
    for (int t = 0; t < 4; ++t) {
        short8_t aF[4], bF[4];
        const int kg = lane >> 4;
        #pragma unroll
        for (int mt = 0; mt < 4; ++mt) {
            int row = wr * 64 + mt * 16 + (lane & 15);
            int pc  = kg ^ swz(row);
            aF[mt] = *reinterpret_cast<const short8_t*>(As + row * 32 + pc * 8);
        }
        #pragma unroll
        for (int nt = 0; nt < 4; ++nt) {
            int row = wc * 64 + nt * 16 + (lane & 15);
            int pc  = kg ^ swz(row);
            bF[nt] = *reinterpret_cast<const short8_t*>(Bs + row * 32 + pc * 8);
        }
        #pragma unroll
        for (int mt = 0; mt < 4; ++mt)
            #pragma unroll
            for (int nt = 0; nt < 4; ++nt)
                acc[mt][nt] = __builtin_amdgcn_mfma_f32_16x16x32_bf16(
                    aF[mt], bF[nt], acc[mt][nt], 0, 0, 0);

        if (t < 3) {
            __syncthreads();
            stage((t + 1) * 32);
            __syncthreads();
        }
    }

    __syncthreads();   // staging dead; repurpose LDS as C tile

    #pragma unroll
    for (int nt = 0; nt < 4; ++nt) {
        int nl = wc * 64 + nt * 16 + (lane & 15);
        float cj = cvec[(size_t)l * N_ + bn0 + nl];
        #pragma unroll
        for (int mt = 0; mt < 4; ++mt) {
            #pragma unroll
            for (int j = 0; j < 4; ++j) {
                int rl = wr * 64 + mt * 16 + (lane >> 4) * 4 + j;
                smem[rl * CP + nl] = f2bf(acc[mt][nt][j] - cj);
            }
        }
    }
    __syncthreads();

    #pragma unroll
    for (int i = 0; i < 8; ++i) {
        int chunk = i * 256 + tid;
        int r = chunk >> 4, cch = chunk & 15;
        ushort8_t v = *reinterpret_cast<const ushort8_t*>(smem + r * CP + cch * 8);
        unsigned short* dst = y16 + ((size_t)((bm0 + r) * L_ + l)) * 8192 + 4096 + bn0 + cch * 8;
        *reinterpret_cast<ushort8_t*>(dst) = v;
    }
}

// ---------------------------------------------------------------------------
// K2 (wave-per-row selector+decoder) -- PACKED-KEY edition.
// |bf16| comparison == unsigned comparison of low-15-bit pattern, so the 64
// approx magnitudes live as 32 packed dwords (am[32], 2 keys each) instead of
// u[8]+a[64] (96 VGPRs -> spilled to scratch in prior rounds). Integer bisect
// on the key space (seeded); pool via ballot/scan; r4-verbatim exact
// recompute; exact rank; direct low-half scatter; fused decode.
// ---------------------------------------------------------------------------
#define POOL 96
#define MARGIN 1.2e-3f

__global__ __launch_bounds__(256) void topk_decode(float* __restrict__ y,
                                                   const float* __restrict__ We,
                                                   const float* __restrict__ WdT,
                                                   const float* __restrict__ kin,
                                                   const float* __restrict__ cvec,
                                                   int* __restrict__ cidx,
                                                   float* __restrict__ cval,
                                                   float* __restrict__ khat,
                                                   float* __restrict__ partial) {
    const int w    = threadIdx.x >> 6;          // wave id in block (0..3)
    const int lane = threadIdx.x & 63;
    const int wid  = (blockIdx.x << 2) + w;     // 0..32767, l-major
    const int l = wid >> 10, b = wid & 1023;
    const int row = b * L_ + l;

    __shared__ __align__(16) float kinS[4][M_];
    __shared__ int   pidxS[4][POOL];
    __shared__ float pexS[4][POOL];
    __shared__ int   sidxS[4][S_];
    __shared__ float svalS[4][S_];

    float* yo = y + (size_t)row * N_;
    const unsigned short* ya = (const unsigned short*)y + (size_t)row * 8192 + 4096;

    kinS[w][lane]      = kin[(size_t)row * M_ + lane];
    kinS[w][lane + 64] = kin[(size_t)row * M_ + lane + 64];

    // load 64 approx values; keep only packed 15-bit magnitude keys (am[32]).
    // Moments/max accumulated on the fly (float temporaries die immediately).
    unsigned am[32];
    float s1 = 0.0f, s2 = 0.0f;
    unsigned mxk = 0u;
    #pragma unroll
    for (int j = 0; j < 8; ++j) {
        uint4_t q = *reinterpret_cast<const uint4_t*>(ya + j * 512 + lane * 8);
        #pragma unroll
        for (int d = 0; d < 4; ++d) {
            unsigned m = q[d] & 0x7FFF7FFFu;
            am[j * 4 + d] = m;
            unsigned k0 = m & 0xFFFFu, k1 = m >> 16;
            mxk = max(mxk, max(k0, k1));
            float v0 = __uint_as_float(k0 << 16);
            float v1 = __uint_as_float(k1 << 16);
            s1 += v0 + v1;
            s2 = fmaf(v0, v0, s2);
            s2 = fmaf(v1, v1, s2);
        }
    }
    // wave reductions (shfl only)
    #pragma unroll
    for (int o = 32; o > 0; o >>= 1) {
        mxk = max(mxk, (unsigned)__shfl_xor((int)mxk, o, 64));
        s1 += __shfl_xor(s1, o, 64);
        s2 += __shfl_xor(s2, o, 64);
    }
    const float mu  = s1 * (1.0f / 4096.0f);
    const float var = fmaxf(s2 * (1.0f / 4096.0f) - mu * mu, 0.0f);
    const float sg  = sqrtf(var);

    // integer bisect on keys: invariant count(key >= lo) >= 32; tighten to <=40.
    // Seeds: bf16 keys of folded-normal quantiles (clamped into (lo, hi]).
    unsigned lo = 0u, hi = mxk;
    int cl = N_;
    for (int it = 0; it < 20 && cl > 40 && lo < hi; ++it) {
        unsigned t;
        if      (it == 0) t = (unsigned)(f2bf(mu + 2.20f * sg) & 0x7FFF);
        else if (it == 1) t = (unsigned)(f2bf(mu + 2.96f * sg) & 0x7FFF);
        else              t = lo + ((hi - lo + 1u) >> 1);
        t = min(max(t, lo + 1u), hi);
        int c = 0;
        #pragma unroll
        for (int i = 0; i < 32; ++i) {
            c += ((am[i] & 0xFFFFu) >= t) ? 1 : 0;
            c += ((am[i] >> 16)     >= t) ? 1 : 0;
        }
        #pragma unroll
        for (int o = 32; o > 0; o >>= 1) c += __shfl_xor(c, o, 64);
        if (c >= S_) { lo = t; cl = c; } else { hi = t - 1u; }
    }

    // pool threshold key: f2bf_rtz(bf2f(lo) - MARGIN)  (truncation rounds
    // DOWN, so key >= thk is a superset of |approx| >= lo_val - MARGIN)
    const float lov = bf2f((unsigned short)lo);
    const float thf = fmaxf(lov - MARGIN, 0.0f);
    const unsigned thk = (__float_as_uint(thf) >> 16) & 0x7FFFu;

    // pool via ballot/scan compaction (no atomics)
    int myc = 0;
    #pragma unroll
    for (int i = 0; i < 32; ++i) {
        myc += ((am[i] & 0xFFFFu) >= thk) ? 1 : 0;
        myc += ((am[i] >> 16)     >= thk) ? 1 : 0;
    }
    int pos = myc;
    #pragma unroll
    for (int o = 1; o < 64; o <<= 1) {
        int t = __shfl_up(pos, o, 64);
        if (lane >= o) pos += t;
    }
    const int base  = pos - myc;                // exclusive prefix
    const int total = __shfl(pos, 63, 64);
    int k = 0;
    #pragma unroll
    for (int j = 0; j < 8; ++j)
        #pragma unroll
        for (int e = 0; e < 8; ++e) {
            unsigned key = (am[j * 4 + (e >> 1)] >> ((e & 1) * 16)) & 0xFFFFu;
            if (key >= thk) {
                int p = base + k;
                if (p < POOL) pidxS[w][p] = j * 512 + lane * 8 + e;
                ++k;
            }
        }
    __asm__ __volatile__("s_waitcnt lgkmcnt(0)" ::: "memory");
    int c = total < POOL ? total : POOL;

    // exact recompute: STRICT ascending-m fmaf chain (bit-identical to r4);
    // float4 loads (We global L2-hot, kin LDS) then 4 in-order scalar fmafs.
    if (lane < c) {
        int n = pidxS[w][lane];
        const float4* wp4 = reinterpret_cast<const float4*>(We + ((size_t)l * N_ + n) * M_);
        const float4* kp4 = reinterpret_cast<const float4*>(kinS[w]);
        float acc = -cvec[(size_t)l * N_ + n];
        #pragma unroll 8
        for (int m4 = 0; m4 < 32; ++m4) {
            float4 wv = wp4[m4], kv = kp4[m4];
            acc = fmaf(wv.x, kv.x, acc);
            acc = fmaf(wv.y, kv.y, acc);
            acc = fmaf(wv.z, kv.z, acc);
            acc = fmaf(wv.w, kv.w, acc);
        }
        pexS[w][lane] = acc;
    }
    if (lane + 64 < c) {
        int n = pidxS[w][lane + 64];
        const float4* wp4 = reinterpret_cast<const float4*>(We + ((size_t)l * N_ + n) * M_);
        const float4* kp4 = reinterpret_cast<const float4*>(kinS[w]);
        float acc = -cvec[(size_t)l * N_ + n];
        #pragma unroll 8
        for (int m4 = 0; m4 < 32; ++m4) {
            float4 wv = wp4[m4], kv = kp4[m4];
            acc = fmaf(wv.x, kv.x, acc);
            acc = fmaf(wv.y, kv.y, acc);
            acc = fmaf(wv.z, kv.z, acc);
            acc = fmaf(wv.w, kv.w, acc);
        }
        pexS[w][lane + 64] = acc;
    }
    __asm__ __volatile__("s_waitcnt lgkmcnt(0)" ::: "memory");

    // exact rank (lowest-index tie-break); winners into LDS lists
    for (int e = lane; e < c; e += 64) {
        float ae = fabsf(pexS[w][e]);
        int   ne = pidxS[w][e];
        int rank = 0;
        for (int j = 0; j < c; ++j) {
            float aj = fabsf(pexS[w][j]);
            rank += ((aj > ae) || (aj == ae && pidxS[w][j] < ne)) ? 1 : 0;
        }
        if (rank < S_) {
            sidxS[w][rank] = ne;
            svalS[w][rank] = pexS[w][e];
        }
    }
    __asm__ __volatile__("s_waitcnt lgkmcnt(0)" ::: "memory");

    // emit winner lists; DIRECT scatter of low-half winners
    if (lane < S_) {
        int n = sidxS[w][lane];
        float v = svalS[w][lane];
        cidx[(size_t)row * S_ + lane] = n;
        cval[(size_t)row * S_ + lane] = v;
        if (n < 2048) yo[n] = v;
    }

    // fused decode: 2 dims per lane; WdT rows L2-resident (l-major)
    const float* wt = WdT + (size_t)l * N_ * M_;
    float acc0 = 0.0f, acc1 = 0.0f;
    #pragma unroll 8
    for (int j = 0; j < S_; ++j) {
        float v = svalS[w][j];
        const float* wrp = wt + (size_t)sidxS[w][j] * M_;
        acc0 = fmaf(v, wrp[lane], acc0);
        acc1 = fmaf(v, wrp[lane + 64], acc1);
    }
    khat[(size_t)row * M_ + lane]      = acc0;
    khat[(size_t)row * M_ + lane + 64] = acc1;
    float r0 = acc0 - kinS[w][lane];
    float r1 = acc1 - kinS[w][lane + 64];
    float s = r0 * r0 + r1 * r1;
    #pragma unroll
    for (int o = 32; o > 0; o >>= 1) s += __shfl_xor(s, o, 64);
    if (lane == 0) partial[row] = s;
}

// ---------------------------------------------------------------------------
// K3: finish_high: zero the HIGH 8KB halves + scatter high winners, fused.
// ---------------------------------------------------------------------------
__global__ __launch_bounds__(256) void finish_high(float* __restrict__ y,
                                                   const int* __restrict__ cidx,
                                                   const float* __restrict__ cval) {
    const int bid = blockIdx.x;                 // 2048 blocks
    const int tid = threadIdx.x;
    const int row0 = bid * 16;
    const float4 z = {0.f, 0.f, 0.f, 0.f};
    #pragma unroll
    for (int i = 0; i < 32; ++i) {
        int g = i * 256 + tid;                  // 0..8191 float4s
        int r = row0 + (g >> 9);
        int slot = g & 511;
        reinterpret_cast<float4*>(y + (size_t)r * N_ + 2048)[slot] = z;
    }
    __syncthreads();    // vmcnt(0) drain before barrier
    #pragma unroll
    for (int i = 0; i < 2; ++i) {
        int e = i * 256 + tid;                  // 0..511 winner entries
        int g = row0 * S_ + e;
        int n = cidx[g];
        if (n >= 2048) {
            int r = row0 + (e >> 5);
            y[(size_t)r * N_ + n] = cval[g];
        }
    }
}

// ---------------------------------------------------------------------------
// K4: deterministic reduction of 32768 partials -> loss (float4 loads)
// ---------------------------------------------------------------------------
__global__ __launch_bounds__(256) void reduce_loss(const float* __restrict__ partial,
                                                   float* __restrict__ out_loss) {
    __shared__ float red[256];
    int tid = threadIdx.x;
    float s = 0.0f;
    for (int i = tid; i < ROWS / 4; i += 256) {
        float4 v = reinterpret_cast<const float4*>(partial)[i];
        s += v.x + v.y + v.z + v.w;
    }
    red[tid] = s;
    __syncthreads();
    for (int off = 128; off > 0; off >>= 1) {
        if (tid < off) red[tid] += red[tid + off];
        __syncthreads();
    }
    if (tid == 0) out_loss[0] = red[0] / (float)((size_t)B_ * L_ * M_);
}

// ---------------------------------------------------------------------------
extern "C" void kernel_launch(void* const* d_in, const int* in_sizes, int n_in,
                              void* d_out, int out_size, void* d_ws, size_t ws_size,
                              hipStream_t stream) {
    const float* kin = (const float*)d_in[0];   // [B][L][M]
    const float* We  = (const float*)d_in[1];   // [L][N][M]
    // d_in[2] = b_e (unused by reference encode())
    const float* Wd  = (const float*)d_in[3];   // [L][M][N]
    const float* bd  = (const float*)d_in[4];   // [L][M]
    // d_in[5] = s (==32, hardcoded)

    float* out   = (float*)d_out;
    float* loss  = out;                                   // [1]
    float* khat  = out + 1;                               // [B*L*M]
    float* y_out = out + 1 + (size_t)B_ * L_ * M_;        // [B*L*N]

    // workspace layout. region0: Wbf (32MB). WdT either aliases region0
    // (small ws; transpose runs after encoder) or lives at +82MB (big ws;
    // transpose joins the prologue). ws_size branch is deterministic.
    char* ws = (char*)d_ws;
    unsigned short* Wbf = (unsigned short*)ws;                   // 32 MiB
    unsigned short* Abf = (unsigned short*)(ws + (64u << 20));   // 8 MiB
    int*   cidx    = (int*)  (ws + (72u << 20));                 // 4 MiB
    float* cval    = (float*)(ws + (76u << 20));                 // 4 MiB
    float* cvec    = (float*)(ws + (80u << 20));                 // 512 KiB
    float* partial = (float*)(ws + (81u << 20));                 // 128 KiB
    const bool wsBig = ws_size >= ((size_t)146u << 20);
    float* WdT = wsBig ? (float*)(ws + ((size_t)82u << 20))      // 64 MiB, no alias
                       : (float*)ws;                             // aliases Wbf

    int nblocks = 26624 + (wsBig ? 16384 : 0);
    prologue<<<nblocks, 256, 0, stream>>>(y_out, We, bd, Wbf, cvec, kin, Abf, Wd, WdT);
    encoder_mfma<<<dim3(N_ / 128, B_ / 128, L_), 256, 0, stream>>>(
        Abf, Wbf, cvec, (unsigned short*)y_out);
    if (!wsBig)
        transpose_wd<<<dim3(N_ / 32, M_ / 32, L_), 256, 0, stream>>>(Wd, WdT);
    topk_decode<<<ROWS / 4, 256, 0, stream>>>(y_out, We, WdT, kin, cvec,
                                              cidx, cval, khat, partial);
    finish_high<<<2048, 256, 0, stream>>>(y_out, cidx, cval);
    reduce_loss<<<1, 256, 0, stream>>>(partial, loss);
}

// Round 18
// 543.142 us; speedup vs baseline: 1.0991x; 1.0991x over previous
//
#include <hip/hip_runtime.h>
#include <hip/hip_bf16.h>

// Problem constants (fixed by the reference)
#define B_ 1024
#define L_ 32
#define M_ 128
#define N_ 4096
#define S_ 32
#define ROWS (B_ * L_)          // 32768 rows of length N_

typedef __attribute__((ext_vector_type(8))) short    short8_t;   // 8 bf16 (4 VGPR)
typedef __attribute__((ext_vector_type(8))) unsigned short ushort8_t;
typedef __attribute__((ext_vector_type(4))) float    f32x4;

__device__ __forceinline__ unsigned short f2bf(float x) {  // RNE bf16
    unsigned u = __float_as_uint(x);
    unsigned r = (u + 0x7FFFu + ((u >> 16) & 1u)) >> 16;
    return (unsigned short)r;
}
__device__ __forceinline__ float bf2f(unsigned short h) {
    return __uint_as_float((unsigned)h << 16);
}

// ---------------------------------------------------------------------------
// P0: PROLOGUE mega-kernel (block-range dispatch over independent jobs):
//   [0,2048)        zero LOW 8KB half of every y row (streaming writes)
//   [2048,10240)    prep_w: Wbf = bf16(We), cvec = b_d . We_n
//   [10240,26624)   prep_a: Abf = bf16(kin), layout [l][b][128]
//   [26624,26624+nT) transpose Wd -> WdT (only when WdT does NOT alias Wbf)
// ---------------------------------------------------------------------------
__global__ __launch_bounds__(256) void prologue(float* __restrict__ y,
                                                const float* __restrict__ We,
                                                const float* __restrict__ bd,
                                                unsigned short* __restrict__ Wbf,
                                                float* __restrict__ cvec,
                                                const float* __restrict__ kin,
                                                unsigned short* __restrict__ Abf,
                                                const float* __restrict__ Wd,
                                                float* __restrict__ WdT) {
    __shared__ float t[32][33];
    const int bid = blockIdx.x;
    const int tid = threadIdx.x;

    if (bid < 2048) {
        const float4 z = {0.f, 0.f, 0.f, 0.f};
        int idx = bid * 256 + tid;
        for (int i = idx; i < ROWS * 512; i += 2048 * 256) {
            int row = i >> 9, slot = i & 511;
            reinterpret_cast<float4*>(y + (size_t)row * N_)[slot] = z;
        }
    } else if (bid < 10240) {
        int wb = bid - 2048;
        int l = wb >> 8, nb = wb & 255;
        int nl = tid >> 4, tt = tid & 15;
        int n = nb * 16 + nl;
        const float* w = We + ((size_t)l * N_ + n) * M_ + tt * 8;
        const float* b = bd + l * M_ + tt * 8;
        float4 w0 = *(const float4*)(w), w1 = *(const float4*)(w + 4);
        float4 b0 = *(const float4*)(b), b1 = *(const float4*)(b + 4);
        ushort8_t o;
        o[0] = f2bf(w0.x); o[1] = f2bf(w0.y); o[2] = f2bf(w0.z); o[3] = f2bf(w0.w);
        o[4] = f2bf(w1.x); o[5] = f2bf(w1.y); o[6] = f2bf(w1.z); o[7] = f2bf(w1.w);
        *reinterpret_cast<ushort8_t*>(Wbf + ((size_t)l * N_ + n) * 128 + tt * 8) = o;
        float s = w0.x*b0.x + w0.y*b0.y + w0.z*b0.z + w0.w*b0.w
                + w1.x*b1.x + w1.y*b1.y + w1.z*b1.z + w1.w*b1.w;
        #pragma unroll
        for (int oo = 8; oo > 0; oo >>= 1) s += __shfl_xor(s, oo, 64);
        if (tt == 0) cvec[(size_t)l * N_ + n] = s;
    } else if (bid < 26624) {
        int g = (bid - 10240) * 256 + tid;        // over B*L*M
        int b = g >> 12, l = (g >> 7) & 31, m = g & 127;
        Abf[(((size_t)l * B_ + b) << 7) + m] = f2bf(kin[g]);
    } else {
        int tb = bid - 26624;
        int l  = tb >> 9;
        int rem = tb & 511;
        int n0 = (rem & 127) * 32, m0 = (rem >> 7) * 32;
        int tx = tid & 31, ty = tid >> 5;
        const float* src = Wd + (size_t)l * M_ * N_;
        for (int i = ty; i < 32; i += 8)
            t[i][tx] = src[(size_t)(m0 + i) * N_ + n0 + tx];
        __syncthreads();
        float* dst = WdT + (size_t)l * N_ * M_;
        for (int i = ty; i < 32; i += 8)
            dst[(size_t)(n0 + i) * M_ + m0 + tx] = t[tx][i];
    }
}

// ---------------------------------------------------------------------------
// K0: standalone transpose (fallback when WdT aliases Wbf)
// ---------------------------------------------------------------------------
__global__ __launch_bounds__(256) void transpose_wd(const float* __restrict__ Wd,
                                                    float* __restrict__ WdT) {
    __shared__ float t[32][33];
    int l = blockIdx.z;
    int n0 = blockIdx.x * 32, m0 = blockIdx.y * 32;
    int tx = threadIdx.x & 31, ty = threadIdx.x >> 5;
    const float* src = Wd + (size_t)l * M_ * N_;
    for (int i = ty; i < 32; i += 8)
        t[i][tx] = src[(size_t)(m0 + i) * N_ + n0 + tx];
    __syncthreads();
    float* dst = WdT + (size_t)l * N_ * M_;
    for (int i = ty; i < 32; i += 8)
        dst[(size_t)(n0 + i) * M_ + m0 + tx] = t[tx][i];
}

// ---------------------------------------------------------------------------
// K1: encoder approx GEMM via MFMA bf16, single term (K=128, 4 BK=32 steps).
// 1-D grid with CHUNKED XCD SWIZZLE: orig = (x&7)*1024 + (x>>3) assigns each
// XCD a contiguous 4-layer chunk -> per-XCD in-flight working set ~2.5MB
// (Wbf 1MB + Abf 256KB per layer) fits the 4MB per-XCD L2, so the 8x/32x
// tile re-reads become L2 hits instead of cross-XCD thrash.
// Epilogue: padded-LDS re-tile -> coalesced 16B stores to the HIGH half.
// ---------------------------------------------------------------------------
__device__ __forceinline__ int swz(int row) { return (row & 3) ^ ((row >> 2) & 3); }

#define CP 136   // C-tile row pitch in shorts

__global__ __launch_bounds__(256) void encoder_mfma(const unsigned short* __restrict__ Abf,
                                                    const unsigned short* __restrict__ Wbf,
                                                    const float* __restrict__ cvec,
                                                    unsigned short* __restrict__ y16) {
    // chunked bijective XCD swizzle over 8192 blocks (8 XCDs x 1024)
    const int orig = ((blockIdx.x & 7) << 10) + (blockIdx.x >> 3);
    const int l    = orig >> 8;                  // layer (4 per XCD chunk)
    const int rem  = orig & 255;
    const int bn0  = (rem & 31) * 128;           // n fastest: A-tile reuse adjacent
    const int bm0  = (rem >> 5) * 128;
    __shared__ __align__(16) unsigned short smem[128 * CP];   // 34.8KB
    unsigned short* As = smem;
    unsigned short* Bs = smem + 128 * 32;
    const int tid  = threadIdx.x;
    const int lane = tid & 63, wave = tid >> 6;
    const int wr = wave >> 1, wc = wave & 1;

    const unsigned short* Ab = Abf + (((size_t)l * B_ + bm0) << 7);
    const unsigned short* Wb = Wbf + (((size_t)l * N_ + bn0) << 7);

    auto stage = [&](int k0) {
        #pragma unroll
        for (int i = 0; i < 2; ++i) {
            int p   = i * 256 + tid;
            int row = p >> 2;
            int lc  = (p & 3) ^ swz(row);
            const unsigned short* g = Ab + ((size_t)row << 7) + k0 + lc * 8;
            unsigned dst = (unsigned)((i * 256 + (tid & ~63)) * 16);
            __builtin_amdgcn_global_load_lds(
                (const __attribute__((address_space(1))) void*)g,
                (__attribute__((address_space(3))) void*)((char*)As + dst), 16, 0, 0);
        }
        #pragma unroll
        for (int i = 0; i < 2; ++i) {
            int p   = i * 256 + tid;
            int row = p >> 2;
            int lc  = (p & 3) ^ swz(row);
            const unsigned short* g = Wb + ((size_t)row << 7) + k0 + lc * 8;
            unsigned dst = (unsigned)((i * 256 + (tid & ~63)) * 16);
            __builtin_amdgcn_global_load_lds(
                (const __attribute__((address_space(1))) void*)g,
                (__attribute__((address_space(3))) void*)((char*)Bs + dst), 16, 0, 0);
        }
    };

    f32x4 acc[4][4];
    #pragma unroll
    for (int i = 0; i < 4; ++i)
        #pragma unroll
        for (int j = 0; j < 4; ++j) acc[i][j] = (f32x4){0.f, 0.f, 0.f, 0.f};

    stage(0);
    __syncthreads();

    #pragma unroll
    for (int t = 0; t < 4; ++t) {
        short8_t aF[4], bF[4];
        const int kg = lane >> 4;
        #pragma unroll
        for (int mt = 0; mt < 4; ++mt) {
            int row = wr * 64 + mt * 16 + (lane & 15);
            int pc  = kg ^ swz(row);
            aF[mt] = *reinterpret_cast<const short8_t*>(As + row * 32 + pc * 8);
        }
        #pragma unroll
        for (int nt = 0; nt < 4; ++nt) {
            int row = wc * 64 + nt * 16 + (lane & 15);
            int pc  = kg ^ swz(row);
            bF[nt] = *reinterpret_cast<const short8_t*>(Bs + row * 32 + pc * 8);
        }
        #pragma unroll
        for (int mt = 0; mt < 4; ++mt)
            #pragma unroll
            for (int nt = 0; nt < 4; ++nt)
                acc[mt][nt] = __builtin_amdgcn_mfma_f32_16x16x32_bf16(
                    aF[mt], bF[nt], acc[mt][nt], 0, 0, 0);

        if (t < 3) {
            __syncthreads();
            stage((t + 1) * 32);
            __syncthreads();
        }
    }

    __syncthreads();   // staging dead; repurpose LDS as C tile

    #pragma unroll
    for (int nt = 0; nt < 4; ++nt) {
        int nl = wc * 64 + nt * 16 + (lane & 15);
        float cj = cvec[(size_t)l * N_ + bn0 + nl];
        #pragma unroll
        for (int mt = 0; mt < 4; ++mt) {
            #pragma unroll
            for (int j = 0; j < 4; ++j) {
                int rl = wr * 64 + mt * 16 + (lane >> 4) * 4 + j;
                smem[rl * CP + nl] = f2bf(acc[mt][nt][j] - cj);
            }
        }
    }
    __syncthreads();

    #pragma unroll
    for (int i = 0; i < 8; ++i) {
        int chunk = i * 256 + tid;
        int r = chunk >> 4, cch = chunk & 15;
        ushort8_t v = *reinterpret_cast<const ushort8_t*>(smem + r * CP + cch * 8);
        unsigned short* dst = y16 + ((size_t)((bm0 + r) * L_ + l)) * 8192 + 4096 + bn0 + cch * 8;
        *reinterpret_cast<ushort8_t*>(dst) = v;
    }
}

// ---------------------------------------------------------------------------
// K2 (wave-per-row selector+decoder, zero block barriers) == ROUND 15 body
// (best measured): seeded bisect, ballot/scan pool, r4-verbatim exact
// recompute, exact rank, direct low-half scatter, fused decode.
// ---------------------------------------------------------------------------
#define POOL 96
#define MARGIN 1.2e-3f

__global__ __launch_bounds__(256) void topk_decode(float* __restrict__ y,
                                                   const float* __restrict__ We,
                                                   const float* __restrict__ WdT,
                                                   const float* __restrict__ kin,
                                                   const float* __restrict__ cvec,
                                                   int* __restrict__ cidx,
                                                   float* __restrict__ cval,
                                                   float* __restrict__ khat,
                                                   float* __restrict__ partial) {
    const int w    = threadIdx.x >> 6;          // wave id in block (0..3)
    const int lane = threadIdx.x & 63;
    const int wid  = (blockIdx.x << 2) + w;     // 0..32767, l-major
    const int l = wid >> 10, b = wid & 1023;
    const int row = b * L_ + l;

    __shared__ __align__(16) float kinS[4][M_];
    __shared__ int   pidxS[4][POOL];
    __shared__ float pexS[4][POOL];
    __shared__ int   sidxS[4][S_];
    __shared__ float svalS[4][S_];

    float* yo = y + (size_t)row * N_;
    const unsigned short* ya = (const unsigned short*)y + (size_t)row * 8192 + 4096;

    kinS[w][lane]      = kin[(size_t)row * M_ + lane];
    kinS[w][lane + 64] = kin[(size_t)row * M_ + lane + 64];

    // load 64 approx values (8 x 16B, coalesced)
    ushort8_t u[8];
    #pragma unroll
    for (int j = 0; j < 8; ++j)
        u[j] = *reinterpret_cast<const ushort8_t*>(ya + j * 512 + lane * 8);
    float a[64];
    #pragma unroll
    for (int j = 0; j < 8; ++j)
        #pragma unroll
        for (int e = 0; e < 8; ++e)
            a[j * 8 + e] = fabsf(bf2f(u[j][e]));

    // wave max + moments (for bisect seeding)
    float mx = 0.0f, s1 = 0.0f, s2 = 0.0f;
    #pragma unroll
    for (int i = 0; i < 64; ++i) {
        mx = fmaxf(mx, a[i]);
        s1 += a[i];
        s2 = fmaf(a[i], a[i], s2);
    }
    #pragma unroll
    for (int o = 32; o > 0; o >>= 1) {
        mx = fmaxf(mx, __shfl_xor(mx, o, 64));
        s1 += __shfl_xor(s1, o, 64);
        s2 += __shfl_xor(s2, o, 64);
    }
    const float mu  = s1 * (1.0f / 4096.0f);
    const float var = fmaxf(s2 * (1.0f / 4096.0f) - mu * mu, 0.0f);
    const float sg  = sqrtf(var);

    // bisect: invariant count(a >= lo) >= 32; tighten until count <= 40.
    float lo = 0.0f, hi = mx;
    int cl = N_;
    for (int it = 0; it < 30 && cl > 40; ++it) {
        float t;
        if      (it == 0) t = mu + 2.20f * sg;
        else if (it == 1) t = mu + 2.96f * sg;
        else              t = 0.5f * (lo + hi);
        t = fminf(fmaxf(t, lo), hi);
        int c = 0;
        #pragma unroll
        for (int i = 0; i < 64; ++i) c += (a[i] >= t) ? 1 : 0;
        #pragma unroll
        for (int o = 32; o > 0; o >>= 1) c += __shfl_xor(c, o, 64);
        if (c >= S_) { lo = t; cl = c; } else { hi = t; }
    }

    // pool via ballot/scan compaction (no atomics)
    const float th = lo - MARGIN;
    int myc = 0;
    #pragma unroll
    for (int i = 0; i < 64; ++i) myc += (a[i] >= th) ? 1 : 0;
    int pos = myc;
    #pragma unroll
    for (int o = 1; o < 64; o <<= 1) {
        int t = __shfl_up(pos, o, 64);
        if (lane >= o) pos += t;
    }
    const int base  = pos - myc;                // exclusive prefix
    const int total = __shfl(pos, 63, 64);
    int k = 0;
    #pragma unroll
    for (int j = 0; j < 8; ++j)
        #pragma unroll
        for (int e = 0; e < 8; ++e)
            if (a[j * 8 + e] >= th) {
                int p = base + k;
                if (p < POOL) pidxS[w][p] = j * 512 + lane * 8 + e;
                ++k;
            }
    __asm__ __volatile__("s_waitcnt lgkmcnt(0)" ::: "memory");
    int c = total < POOL ? total : POOL;

    // exact recompute: STRICT ascending-m fmaf chain (bit-identical to r4);
    // float4 loads (We global L2-hot, kin LDS) then 4 in-order scalar fmafs.
    if (lane < c) {
        int n = pidxS[w][lane];
        const float4* wp4 = reinterpret_cast<const float4*>(We + ((size_t)l * N_ + n) * M_);
        const float4* kp4 = reinterpret_cast<const float4*>(kinS[w]);
        float acc = -cvec[(size_t)l * N_ + n];
        #pragma unroll 8
        for (int m4 = 0; m4 < 32; ++m4) {
            float4 wv = wp4[m4], kv = kp4[m4];
            acc = fmaf(wv.x, kv.x, acc);
            acc = fmaf(wv.y, kv.y, acc);
            acc = fmaf(wv.z, kv.z, acc);
            acc = fmaf(wv.w, kv.w, acc);
        }
        pexS[w][lane] = acc;
    }
    if (lane + 64 < c) {
        int n = pidxS[w][lane + 64];
        const float4* wp4 = reinterpret_cast<const float4*>(We + ((size_t)l * N_ + n) * M_);
        const float4* kp4 = reinterpret_cast<const float4*>(kinS[w]);
        float acc = -cvec[(size_t)l * N_ + n];
        #pragma unroll 8
        for (int m4 = 0; m4 < 32; ++m4) {
            float4 wv = wp4[m4], kv = kp4[m4];
            acc = fmaf(wv.x, kv.x, acc);
            acc = fmaf(wv.y, kv.y, acc);
            acc = fmaf(wv.z, kv.z, acc);
            acc = fmaf(wv.w, kv.w, acc);
        }
        pexS[w][lane + 64] = acc;
    }
    __asm__ __volatile__("s_waitcnt lgkmcnt(0)" ::: "memory");

    // exact rank (lowest-index tie-break); winners into LDS lists
    for (int e = lane; e < c; e += 64) {
        float ae = fabsf(pexS[w][e]);
        int   ne = pidxS[w][e];
        int rank = 0;
        for (int j = 0; j < c; ++j) {
            float aj = fabsf(pexS[w][j]);
            rank += ((aj > ae) || (aj == ae && pidxS[w][j] < ne)) ? 1 : 0;
        }
        if (rank < S_) {
            sidxS[w][rank] = ne;
            svalS[w][rank] = pexS[w][e];
        }
    }
    __asm__ __volatile__("s_waitcnt lgkmcnt(0)" ::: "memory");

    // emit winner lists; DIRECT scatter of low-half winners
    if (lane < S_) {
        int n = sidxS[w][lane];
        float v = svalS[w][lane];
        cidx[(size_t)row * S_ + lane] = n;
        cval[(size_t)row * S_ + lane] = v;
        if (n < 2048) yo[n] = v;
    }

    // fused decode: 2 dims per lane; WdT rows L2-resident (l-major)
    const float* wt = WdT + (size_t)l * N_ * M_;
    float acc0 = 0.0f, acc1 = 0.0f;
    #pragma unroll 8
    for (int j = 0; j < S_; ++j) {
        float v = svalS[w][j];
        const float* wrp = wt + (size_t)sidxS[w][j] * M_;
        acc0 = fmaf(v, wrp[lane], acc0);
        acc1 = fmaf(v, wrp[lane + 64], acc1);
    }
    khat[(size_t)row * M_ + lane]      = acc0;
    khat[(size_t)row * M_ + lane + 64] = acc1;
    float r0 = acc0 - kinS[w][lane];
    float r1 = acc1 - kinS[w][lane + 64];
    float s = r0 * r0 + r1 * r1;
    #pragma unroll
    for (int o = 32; o > 0; o >>= 1) s += __shfl_xor(s, o, 64);
    if (lane == 0) partial[row] = s;
}

// ---------------------------------------------------------------------------
// K3: finish_high: zero the HIGH 8KB halves + scatter high winners, fused.
// ---------------------------------------------------------------------------
__global__ __launch_bounds__(256) void finish_high(float* __restrict__ y,
                                                   const int* __restrict__ cidx,
                                                   const float* __restrict__ cval) {
    const int bid = blockIdx.x;                 // 2048 blocks
    const int tid = threadIdx.x;
    const int row0 = bid * 16;
    const float4 z = {0.f, 0.f, 0.f, 0.f};
    #pragma unroll
    for (int i = 0; i < 32; ++i) {
        int g = i * 256 + tid;                  // 0..8191 float4s
        int r = row0 + (g >> 9);
        int slot = g & 511;
        reinterpret_cast<float4*>(y + (size_t)r * N_ + 2048)[slot] = z;
    }
    __syncthreads();    // vmcnt(0) drain before barrier
    #pragma unroll
    for (int i = 0; i < 2; ++i) {
        int e = i * 256 + tid;                  // 0..511 winner entries
        int g = row0 * S_ + e;
        int n = cidx[g];
        if (n >= 2048) {
            int r = row0 + (e >> 5);
            y[(size_t)r * N_ + n] = cval[g];
        }
    }
}

// ---------------------------------------------------------------------------
// K4: deterministic reduction of 32768 partials -> loss (float4 loads)
// ---------------------------------------------------------------------------
__global__ __launch_bounds__(256) void reduce_loss(const float* __restrict__ partial,
                                                   float* __restrict__ out_loss) {
    __shared__ float red[256];
    int tid = threadIdx.x;
    float s = 0.0f;
    for (int i = tid; i < ROWS / 4; i += 256) {
        float4 v = reinterpret_cast<const float4*>(partial)[i];
        s += v.x + v.y + v.z + v.w;
    }
    red[tid] = s;
    __syncthreads();
    for (int off = 128; off > 0; off >>= 1) {
        if (tid < off) red[tid] += red[tid + off];
        __syncthreads();
    }
    if (tid == 0) out_loss[0] = red[0] / (float)((size_t)B_ * L_ * M_);
}

// ---------------------------------------------------------------------------
extern "C" void kernel_launch(void* const* d_in, const int* in_sizes, int n_in,
                              void* d_out, int out_size, void* d_ws, size_t ws_size,
                              hipStream_t stream) {
    const float* kin = (const float*)d_in[0];   // [B][L][M]
    const float* We  = (const float*)d_in[1];   // [L][N][M]
    // d_in[2] = b_e (unused by reference encode())
    const float* Wd  = (const float*)d_in[3];   // [L][M][N]
    const float* bd  = (const float*)d_in[4];   // [L][M]
    // d_in[5] = s (==32, hardcoded)

    float* out   = (float*)d_out;
    float* loss  = out;                                   // [1]
    float* khat  = out + 1;                               // [B*L*M]
    float* y_out = out + 1 + (size_t)B_ * L_ * M_;        // [B*L*N]

    // workspace layout. region0: Wbf (32MB). WdT either aliases region0
    // (small ws; transpose runs after encoder) or lives at +82MB (big ws;
    // transpose joins the prologue). ws_size branch is deterministic.
    char* ws = (char*)d_ws;
    unsigned short* Wbf = (unsigned short*)ws;                   // 32 MiB
    unsigned short* Abf = (unsigned short*)(ws + (64u << 20));   // 8 MiB
    int*   cidx    = (int*)  (ws + (72u << 20));                 // 4 MiB
    float* cval    = (float*)(ws + (76u << 20));                 // 4 MiB
    float* cvec    = (float*)(ws + (80u << 20));                 // 512 KiB
    float* partial = (float*)(ws + (81u << 20));                 // 128 KiB
    const bool wsBig = ws_size >= ((size_t)146u << 20);
    float* WdT = wsBig ? (float*)(ws + ((size_t)82u << 20))      // 64 MiB, no alias
                       : (float*)ws;                             // aliases Wbf

    int nblocks = 26624 + (wsBig ? 16384 : 0);
    prologue<<<nblocks, 256, 0, stream>>>(y_out, We, bd, Wbf, cvec, kin, Abf, Wd, WdT);
    // encoder: 1-D grid, chunked XCD swizzle (4 layers per XCD chunk)
    encoder_mfma<<<8192, 256, 0, stream>>>(Abf, Wbf, cvec, (unsigned short*)y_out);
    if (!wsBig)
        transpose_wd<<<dim3(N_ / 32, M_ / 32, L_), 256, 0, stream>>>(Wd, WdT);
    topk_decode<<<ROWS / 4, 256, 0, stream>>>(y_out, We, WdT, kin, cvec,
                                              cidx, cval, khat, partial);
    finish_high<<<2048, 256, 0, stream>>>(y_out, cidx, cval);
    reduce_loss<<<1, 256, 0, stream>>>(partial, loss);
}

// Round 19
// 541.368 us; speedup vs baseline: 1.1027x; 1.0033x over previous
//
#include <hip/hip_runtime.h>
#include <hip/hip_bf16.h>

// Problem constants (fixed by the reference)
#define B_ 1024
#define L_ 32
#define M_ 128
#define N_ 4096
#define S_ 32
#define ROWS (B_ * L_)          // 32768 rows of length N_

typedef __attribute__((ext_vector_type(8))) short    short8_t;   // 8 bf16 (4 VGPR)
typedef __attribute__((ext_vector_type(8))) unsigned short ushort8_t;
typedef __attribute__((ext_vector_type(4))) float    f32x4;

__device__ __forceinline__ unsigned short f2bf(float x) {  // RNE bf16
    unsigned u = __float_as_uint(x);
    unsigned r = (u + 0x7FFFu + ((u >> 16) & 1u)) >> 16;
    return (unsigned short)r;
}
__device__ __forceinline__ float bf2f(unsigned short h) {
    return __uint_as_float((unsigned)h << 16);
}

// ---------------------------------------------------------------------------
// P0: PROLOGUE mega-kernel (block-range dispatch over independent jobs):
//   [0,2048)        zero LOW 8KB half of every y row (streaming writes)
//   [2048,10240)    prep_w: Wbf = bf16(We), cvec = b_d . We_n
//   [10240,26624)   prep_a: Abf = bf16(kin), layout [l][b][128]
//   [26624,26624+nT) transpose Wd -> WdT (only when WdT does NOT alias Wbf).
// Hoisting the transpose before the encoder also keeps the encoder's approx
// output L3-resident for topk (no 128MB transpose stream between them).
// ---------------------------------------------------------------------------
__global__ __launch_bounds__(256) void prologue(float* __restrict__ y,
                                                const float* __restrict__ We,
                                                const float* __restrict__ bd,
                                                unsigned short* __restrict__ Wbf,
                                                float* __restrict__ cvec,
                                                const float* __restrict__ kin,
                                                unsigned short* __restrict__ Abf,
                                                const float* __restrict__ Wd,
                                                float* __restrict__ WdT) {
    __shared__ float t[32][33];
    const int bid = blockIdx.x;
    const int tid = threadIdx.x;

    if (bid < 2048) {
        const float4 z = {0.f, 0.f, 0.f, 0.f};
        int idx = bid * 256 + tid;
        for (int i = idx; i < ROWS * 512; i += 2048 * 256) {
            int row = i >> 9, slot = i & 511;
            reinterpret_cast<float4*>(y + (size_t)row * N_)[slot] = z;
        }
    } else if (bid < 10240) {
        int wb = bid - 2048;
        int l = wb >> 8, nb = wb & 255;
        int nl = tid >> 4, tt = tid & 15;
        int n = nb * 16 + nl;
        const float* w = We + ((size_t)l * N_ + n) * M_ + tt * 8;
        const float* b = bd + l * M_ + tt * 8;
        float4 w0 = *(const float4*)(w), w1 = *(const float4*)(w + 4);
        float4 b0 = *(const float4*)(b), b1 = *(const float4*)(b + 4);
        ushort8_t o;
        o[0] = f2bf(w0.x); o[1] = f2bf(w0.y); o[2] = f2bf(w0.z); o[3] = f2bf(w0.w);
        o[4] = f2bf(w1.x); o[5] = f2bf(w1.y); o[6] = f2bf(w1.z); o[7] = f2bf(w1.w);
        *reinterpret_cast<ushort8_t*>(Wbf + ((size_t)l * N_ + n) * 128 + tt * 8) = o;
        float s = w0.x*b0.x + w0.y*b0.y + w0.z*b0.z + w0.w*b0.w
                + w1.x*b1.x + w1.y*b1.y + w1.z*b1.z + w1.w*b1.w;
        #pragma unroll
        for (int oo = 8; oo > 0; oo >>= 1) s += __shfl_xor(s, oo, 64);
        if (tt == 0) cvec[(size_t)l * N_ + n] = s;
    } else if (bid < 26624) {
        int g = (bid - 10240) * 256 + tid;        // over B*L*M
        int b = g >> 12, l = (g >> 7) & 31, m = g & 127;
        Abf[(((size_t)l * B_ + b) << 7) + m] = f2bf(kin[g]);
    } else {
        int tb = bid - 26624;
        int l  = tb >> 9;
        int rem = tb & 511;
        int n0 = (rem & 127) * 32, m0 = (rem >> 7) * 32;
        int tx = tid & 31, ty = tid >> 5;
        const float* src = Wd + (size_t)l * M_ * N_;
        for (int i = ty; i < 32; i += 8)
            t[i][tx] = src[(size_t)(m0 + i) * N_ + n0 + tx];
        __syncthreads();
        float* dst = WdT + (size_t)l * N_ * M_;
        for (int i = ty; i < 32; i += 8)
            dst[(size_t)(n0 + i) * M_ + m0 + tx] = t[tx][i];
    }
}

// ---------------------------------------------------------------------------
// K0: standalone transpose (fallback when WdT aliases Wbf)
// ---------------------------------------------------------------------------
__global__ __launch_bounds__(256) void transpose_wd(const float* __restrict__ Wd,
                                                    float* __restrict__ WdT) {
    __shared__ float t[32][33];
    int l = blockIdx.z;
    int n0 = blockIdx.x * 32, m0 = blockIdx.y * 32;
    int tx = threadIdx.x & 31, ty = threadIdx.x >> 5;
    const float* src = Wd + (size_t)l * M_ * N_;
    for (int i = ty; i < 32; i += 8)
        t[i][tx] = src[(size_t)(m0 + i) * N_ + n0 + tx];
    __syncthreads();
    float* dst = WdT + (size_t)l * N_ * M_;
    for (int i = ty; i < 32; i += 8)
        dst[(size_t)(n0 + i) * M_ + m0 + tx] = t[tx][i];
}

// ---------------------------------------------------------------------------
// K1: encoder approx GEMM via MFMA bf16, single term (K=128, 4 BK=32 steps).
// 1-D grid with CHUNKED XCD SWIZZLE (r18, measured -40us): orig =
// (x&7)*1024 + (x>>3); per-XCD working set ~2.5MB fits the 4MB L2.
// Epilogue: padded-LDS re-tile -> coalesced 16B stores to the HIGH half.
// Write time-order (for topk recency mapping): per chunk, l ascending then
// bm ascending.
// ---------------------------------------------------------------------------
__device__ __forceinline__ int swz(int row) { return (row & 3) ^ ((row >> 2) & 3); }

#define CP 136   // C-tile row pitch in shorts

__global__ __launch_bounds__(256) void encoder_mfma(const unsigned short* __restrict__ Abf,
                                                    const unsigned short* __restrict__ Wbf,
                                                    const float* __restrict__ cvec,
                                                    unsigned short* __restrict__ y16) {
    const int orig = ((blockIdx.x & 7) << 10) + (blockIdx.x >> 3);
    const int l    = orig >> 8;                  // layer (4 per XCD chunk)
    const int rem  = orig & 255;
    const int bn0  = (rem & 31) * 128;           // n fastest
    const int bm0  = (rem >> 5) * 128;
    __shared__ __align__(16) unsigned short smem[128 * CP];   // 34.8KB
    unsigned short* As = smem;
    unsigned short* Bs = smem + 128 * 32;
    const int tid  = threadIdx.x;
    const int lane = tid & 63, wave = tid >> 6;
    const int wr = wave >> 1, wc = wave & 1;

    const unsigned short* Ab = Abf + (((size_t)l * B_ + bm0) << 7);
    const unsigned short* Wb = Wbf + (((size_t)l * N_ + bn0) << 7);

    auto stage = [&](int k0) {
        #pragma unroll
        for (int i = 0; i < 2; ++i) {
            int p   = i * 256 + tid;
            int row = p >> 2;
            int lc  = (p & 3) ^ swz(row);
            const unsigned short* g = Ab + ((size_t)row << 7) + k0 + lc * 8;
            unsigned dst = (unsigned)((i * 256 + (tid & ~63)) * 16);
            __builtin_amdgcn_global_load_lds(
                (const __attribute__((address_space(1))) void*)g,
                (__attribute__((address_space(3))) void*)((char*)As + dst), 16, 0, 0);
        }
        #pragma unroll
        for (int i = 0; i < 2; ++i) {
            int p   = i * 256 + tid;
            int row = p >> 2;
            int lc  = (p & 3) ^ swz(row);
            const unsigned short* g = Wb + ((size_t)row << 7) + k0 + lc * 8;
            unsigned dst = (unsigned)((i * 256 + (tid & ~63)) * 16);
            __builtin_amdgcn_global_load_lds(
                (const __attribute__((address_space(1))) void*)g,
                (__attribute__((address_space(3))) void*)((char*)Bs + dst), 16, 0, 0);
        }
    };

    f32x4 acc[4][4];
    #pragma unroll
    for (int i = 0; i < 4; ++i)
        #pragma unroll
        for (int j = 0; j < 4; ++j) acc[i][j] = (f32x4){0.f, 0.f, 0.f, 0.f};

    stage(0);
    __syncthreads();

    #pragma unroll
    for (int t = 0; t < 4; ++t) {
        short8_t aF[4], bF[4];
        const int kg = lane >> 4;
        #pragma unroll
        for (int mt = 0; mt < 4; ++mt) {
            int row = wr * 64 + mt * 16 + (lane & 15);
            int pc  = kg ^ swz(row);
            aF[mt] = *reinterpret_cast<const short8_t*>(As + row * 32 + pc * 8);
        }
        #pragma unroll
        for (int nt = 0; nt < 4; ++nt) {
            int row = wc * 64 + nt * 16 + (lane & 15);
            int pc  = kg ^ swz(row);
            bF[nt] = *reinterpret_cast<const short8_t*>(Bs + row * 32 + pc * 8);
        }
        #pragma unroll
        for (int mt = 0; mt < 4; ++mt)
            #pragma unroll
            for (int nt = 0; nt < 4; ++nt)
                acc[mt][nt] = __builtin_amdgcn_mfma_f32_16x16x32_bf16(
                    aF[mt], bF[nt], acc[mt][nt], 0, 0, 0);

        if (t < 3) {
            __syncthreads();
            stage((t + 1) * 32);
            __syncthreads();
        }
    }

    __syncthreads();   // staging dead; repurpose LDS as C tile

    #pragma unroll
    for (int nt = 0; nt < 4; ++nt) {
        int nl = wc * 64 + nt * 16 + (lane & 15);
        float cj = cvec[(size_t)l * N_ + bn0 + nl];
        #pragma unroll
        for (int mt = 0; mt < 4; ++mt) {
            #pragma unroll
            for (int j = 0; j < 4; ++j) {
                int rl = wr * 64 + mt * 16 + (lane >> 4) * 4 + j;
                smem[rl * CP + nl] = f2bf(acc[mt][nt][j] - cj);
            }
        }
    }
    __syncthreads();

    #pragma unroll
    for (int i = 0; i < 8; ++i) {
        int chunk = i * 256 + tid;
        int r = chunk >> 4, cch = chunk & 15;
        ushort8_t v = *reinterpret_cast<const ushort8_t*>(smem + r * CP + cch * 8);
        unsigned short* dst = y16 + ((size_t)((bm0 + r) * L_ + l)) * 8192 + 4096 + bn0 + cch * 8;
        *reinterpret_cast<ushort8_t*>(dst) = v;
    }
}

// ---------------------------------------------------------------------------
// K2 (wave-per-row selector+decoder, zero block barriers) == ROUND 15 body
// with REVERSE-RECENCY row mapping: blocks dispatched first read the rows the
// encoder wrote LAST (phase p=3..0, bm descending) -> approx reads hit L3.
// Consecutive 256 blocks still share one layer -> L2 locality for We/WdT.
// ---------------------------------------------------------------------------
#define POOL 96
#define MARGIN 1.2e-3f

__global__ __launch_bounds__(256) void topk_decode(float* __restrict__ y,
                                                   const float* __restrict__ We,
                                                   const float* __restrict__ WdT,
                                                   const float* __restrict__ kin,
                                                   const float* __restrict__ cvec,
                                                   int* __restrict__ cidx,
                                                   float* __restrict__ cval,
                                                   float* __restrict__ khat,
                                                   float* __restrict__ partial) {
    const int w    = threadIdx.x >> 6;          // wave id in block (0..3)
    const int lane = threadIdx.x & 63;
    // reverse-recency mapping (bijective over 8192 blocks x 4 waves = 32768):
    const int i  = blockIdx.x;
    const int p  = 3 - (i >> 11);               // encoder layer-in-chunk, freshest first
    const int x  = (i >> 8) & 7;                // encoder XCD chunk
    const int l  = 4 * x + p;
    const int j  = i & 255;
    const int bm = 7 - (j >> 5);                // encoder bm, freshest first
    const int bq = j & 31;
    const int b  = bm * 128 + bq * 4 + w;
    const int row = b * L_ + l;

    __shared__ __align__(16) float kinS[4][M_];
    __shared__ int   pidxS[4][POOL];
    __shared__ float pexS[4][POOL];
    __shared__ int   sidxS[4][S_];
    __shared__ float svalS[4][S_];

    float* yo = y + (size_t)row * N_;
    const unsigned short* ya = (const unsigned short*)y + (size_t)row * 8192 + 4096;

    kinS[w][lane]      = kin[(size_t)row * M_ + lane];
    kinS[w][lane + 64] = kin[(size_t)row * M_ + lane + 64];

    // load 64 approx values (8 x 16B, coalesced)
    ushort8_t u[8];
    #pragma unroll
    for (int jj = 0; jj < 8; ++jj)
        u[jj] = *reinterpret_cast<const ushort8_t*>(ya + jj * 512 + lane * 8);
    float a[64];
    #pragma unroll
    for (int jj = 0; jj < 8; ++jj)
        #pragma unroll
        for (int e = 0; e < 8; ++e)
            a[jj * 8 + e] = fabsf(bf2f(u[jj][e]));

    // wave max + moments (for bisect seeding)
    float mx = 0.0f, s1 = 0.0f, s2 = 0.0f;
    #pragma unroll
    for (int ii = 0; ii < 64; ++ii) {
        mx = fmaxf(mx, a[ii]);
        s1 += a[ii];
        s2 = fmaf(a[ii], a[ii], s2);
    }
    #pragma unroll
    for (int o = 32; o > 0; o >>= 1) {
        mx = fmaxf(mx, __shfl_xor(mx, o, 64));
        s1 += __shfl_xor(s1, o, 64);
        s2 += __shfl_xor(s2, o, 64);
    }
    const float mu  = s1 * (1.0f / 4096.0f);
    const float var = fmaxf(s2 * (1.0f / 4096.0f) - mu * mu, 0.0f);
    const float sg  = sqrtf(var);

    // bisect: invariant count(a >= lo) >= 32; tighten until count <= 40.
    float lo = 0.0f, hi = mx;
    int cl = N_;
    for (int it = 0; it < 30 && cl > 40; ++it) {
        float t;
        if      (it == 0) t = mu + 2.20f * sg;
        else if (it == 1) t = mu + 2.96f * sg;
        else              t = 0.5f * (lo + hi);
        t = fminf(fmaxf(t, lo), hi);
        int c = 0;
        #pragma unroll
        for (int ii = 0; ii < 64; ++ii) c += (a[ii] >= t) ? 1 : 0;
        #pragma unroll
        for (int o = 32; o > 0; o >>= 1) c += __shfl_xor(c, o, 64);
        if (c >= S_) { lo = t; cl = c; } else { hi = t; }
    }

    // pool via ballot/scan compaction (no atomics)
    const float th = lo - MARGIN;
    int myc = 0;
    #pragma unroll
    for (int ii = 0; ii < 64; ++ii) myc += (a[ii] >= th) ? 1 : 0;
    int pos = myc;
    #pragma unroll
    for (int o = 1; o < 64; o <<= 1) {
        int t = __shfl_up(pos, o, 64);
        if (lane >= o) pos += t;
    }
    const int base  = pos - myc;                // exclusive prefix
    const int total = __shfl(pos, 63, 64);
    int k = 0;
    #pragma unroll
    for (int jj = 0; jj < 8; ++jj)
        #pragma unroll
        for (int e = 0; e < 8; ++e)
            if (a[jj * 8 + e] >= th) {
                int pp = base + k;
                if (pp < POOL) pidxS[w][pp] = jj * 512 + lane * 8 + e;
                ++k;
            }
    __asm__ __volatile__("s_waitcnt lgkmcnt(0)" ::: "memory");
    int c = total < POOL ? total : POOL;

    // exact recompute: STRICT ascending-m fmaf chain (bit-identical to r4);
    // float4 loads (We global L2-hot, kin LDS) then 4 in-order scalar fmafs.
    if (lane < c) {
        int n = pidxS[w][lane];
        const float4* wp4 = reinterpret_cast<const float4*>(We + ((size_t)l * N_ + n) * M_);
        const float4* kp4 = reinterpret_cast<const float4*>(kinS[w]);
        float acc = -cvec[(size_t)l * N_ + n];
        #pragma unroll 8
        for (int m4 = 0; m4 < 32; ++m4) {
            float4 wv = wp4[m4], kv = kp4[m4];
            acc = fmaf(wv.x, kv.x, acc);
            acc = fmaf(wv.y, kv.y, acc);
            acc = fmaf(wv.z, kv.z, acc);
            acc = fmaf(wv.w, kv.w, acc);
        }
        pexS[w][lane] = acc;
    }
    if (lane + 64 < c) {
        int n = pidxS[w][lane + 64];
        const float4* wp4 = reinterpret_cast<const float4*>(We + ((size_t)l * N_ + n) * M_);
        const float4* kp4 = reinterpret_cast<const float4*>(kinS[w]);
        float acc = -cvec[(size_t)l * N_ + n];
        #pragma unroll 8
        for (int m4 = 0; m4 < 32; ++m4) {
            float4 wv = wp4[m4], kv = kp4[m4];
            acc = fmaf(wv.x, kv.x, acc);
            acc = fmaf(wv.y, kv.y, acc);
            acc = fmaf(wv.z, kv.z, acc);
            acc = fmaf(wv.w, kv.w, acc);
        }
        pexS[w][lane + 64] = acc;
    }
    __asm__ __volatile__("s_waitcnt lgkmcnt(0)" ::: "memory");

    // exact rank (lowest-index tie-break); winners into LDS lists
    for (int e = lane; e < c; e += 64) {
        float ae = fabsf(pexS[w][e]);
        int   ne = pidxS[w][e];
        int rank = 0;
        for (int jj = 0; jj < c; ++jj) {
            float aj = fabsf(pexS[w][jj]);
            rank += ((aj > ae) || (aj == ae && pidxS[w][jj] < ne)) ? 1 : 0;
        }
        if (rank < S_) {
            sidxS[w][rank] = ne;
            svalS[w][rank] = pexS[w][e];
        }
    }
    __asm__ __volatile__("s_waitcnt lgkmcnt(0)" ::: "memory");

    // emit winner lists; DIRECT scatter of low-half winners
    if (lane < S_) {
        int n = sidxS[w][lane];
        float v = svalS[w][lane];
        cidx[(size_t)row * S_ + lane] = n;
        cval[(size_t)row * S_ + lane] = v;
        if (n < 2048) yo[n] = v;
    }

    // fused decode: 2 dims per lane; WdT rows L2-resident
    const float* wt = WdT + (size_t)l * N_ * M_;
    float acc0 = 0.0f, acc1 = 0.0f;
    #pragma unroll 8
    for (int jj = 0; jj < S_; ++jj) {
        float v = svalS[w][jj];
        const float* wrp = wt + (size_t)sidxS[w][jj] * M_;
        acc0 = fmaf(v, wrp[lane], acc0);
        acc1 = fmaf(v, wrp[lane + 64], acc1);
    }
    khat[(size_t)row * M_ + lane]      = acc0;
    khat[(size_t)row * M_ + lane + 64] = acc1;
    float r0 = acc0 - kinS[w][lane];
    float r1 = acc1 - kinS[w][lane + 64];
    float s = r0 * r0 + r1 * r1;
    #pragma unroll
    for (int o = 32; o > 0; o >>= 1) s += __shfl_xor(s, o, 64);
    if (lane == 0) partial[row] = s;
}

// ---------------------------------------------------------------------------
// K3: finish_high: zero the HIGH 8KB halves + scatter high winners, fused.
// ---------------------------------------------------------------------------
__global__ __launch_bounds__(256) void finish_high(float* __restrict__ y,
                                                   const int* __restrict__ cidx,
                                                   const float* __restrict__ cval) {
    const int bid = blockIdx.x;                 // 2048 blocks
    const int tid = threadIdx.x;
    const int row0 = bid * 16;
    const float4 z = {0.f, 0.f, 0.f, 0.f};
    #pragma unroll
    for (int i = 0; i < 32; ++i) {
        int g = i * 256 + tid;                  // 0..8191 float4s
        int r = row0 + (g >> 9);
        int slot = g & 511;
        reinterpret_cast<float4*>(y + (size_t)r * N_ + 2048)[slot] = z;
    }
    __syncthreads();    // vmcnt(0) drain before barrier
    #pragma unroll
    for (int i = 0; i < 2; ++i) {
        int e = i * 256 + tid;                  // 0..511 winner entries
        int g = row0 * S_ + e;
        int n = cidx[g];
        if (n >= 2048) {
            int r = row0 + (e >> 5);
            y[(size_t)r * N_ + n] = cval[g];
        }
    }
}

// ---------------------------------------------------------------------------
// K4: deterministic reduction of 32768 partials -> loss (float4 loads)
// ---------------------------------------------------------------------------
__global__ __launch_bounds__(256) void reduce_loss(const float* __restrict__ partial,
                                                   float* __restrict__ out_loss) {
    __shared__ float red[256];
    int tid = threadIdx.x;
    float s = 0.0f;
    for (int i = tid; i < ROWS / 4; i += 256) {
        float4 v = reinterpret_cast<const float4*>(partial)[i];
        s += v.x + v.y + v.z + v.w;
    }
    red[tid] = s;
    __syncthreads();
    for (int off = 128; off > 0; off >>= 1) {
        if (tid < off) red[tid] += red[tid + off];
        __syncthreads();
    }
    if (tid == 0) out_loss[0] = red[0] / (float)((size_t)B_ * L_ * M_);
}

// ---------------------------------------------------------------------------
extern "C" void kernel_launch(void* const* d_in, const int* in_sizes, int n_in,
                              void* d_out, int out_size, void* d_ws, size_t ws_size,
                              hipStream_t stream) {
    const float* kin = (const float*)d_in[0];   // [B][L][M]
    const float* We  = (const float*)d_in[1];   // [L][N][M]
    // d_in[2] = b_e (unused by reference encode())
    const float* Wd  = (const float*)d_in[3];   // [L][M][N]
    const float* bd  = (const float*)d_in[4];   // [L][M]
    // d_in[5] = s (==32, hardcoded)

    float* out   = (float*)d_out;
    float* loss  = out;                                   // [1]
    float* khat  = out + 1;                               // [B*L*M]
    float* y_out = out + 1 + (size_t)B_ * L_ * M_;        // [B*L*N]

    char* ws = (char*)d_ws;
    const bool wsBig = ws_size >= ((size_t)113u << 20);

    unsigned short* Wbf;
    unsigned short* Abf;
    int*   cidx;
    float* cval;
    float* cvec;
    float* partial;
    float* WdT;

    if (wsBig) {
        // tight non-aliasing layout (113 MiB): transpose joins the prologue
        Wbf     = (unsigned short*)ws;                       // 0   .. 32 MiB
        Abf     = (unsigned short*)(ws + (32u << 20));       // 32  .. 40 MiB
        cidx    = (int*)  (ws + (40u << 20));                // 40  .. 44 MiB
        cval    = (float*)(ws + (44u << 20));                // 44  .. 48 MiB
        cvec    = (float*)(ws + (48u << 20));                // 48  .. 48.5 MiB
        partial = (float*)(ws + (48u << 20) + (512u << 10)); // 48.5.. 49 MiB
        WdT     = (float*)(ws + (49u << 20));                // 49  .. 113 MiB
    } else {
        // r18 fallback layout: WdT aliases Wbf; transpose runs after encoder
        Wbf     = (unsigned short*)ws;                       // 32 MiB
        Abf     = (unsigned short*)(ws + (64u << 20));       // 8 MiB
        cidx    = (int*)  (ws + (72u << 20));                // 4 MiB
        cval    = (float*)(ws + (76u << 20));                // 4 MiB
        cvec    = (float*)(ws + (80u << 20));                // 512 KiB
        partial = (float*)(ws + (81u << 20));                // 128 KiB
        WdT     = (float*)ws;                                // aliases Wbf
    }

    int nblocks = 26624 + (wsBig ? 16384 : 0);
    prologue<<<nblocks, 256, 0, stream>>>(y_out, We, bd, Wbf, cvec, kin, Abf, Wd, WdT);
    // encoder: 1-D grid, chunked XCD swizzle (4 layers per XCD chunk)
    encoder_mfma<<<8192, 256, 0, stream>>>(Abf, Wbf, cvec, (unsigned short*)y_out);
    if (!wsBig)
        transpose_wd<<<dim3(N_ / 32, M_ / 32, L_), 256, 0, stream>>>(Wd, WdT);
    topk_decode<<<ROWS / 4, 256, 0, stream>>>(y_out, We, WdT, kin, cvec,
                                              cidx, cval, khat, partial);
    finish_high<<<2048, 256, 0, stream>>>(y_out, cidx, cval);
    reduce_loss<<<1, 256, 0, stream>>>(partial, loss);
}

// Round 20
// 538.555 us; speedup vs baseline: 1.1085x; 1.0052x over previous
//
#include <hip/hip_runtime.h>
#include <hip/hip_bf16.h>

// Problem constants (fixed by the reference)
#define B_ 1024
#define L_ 32
#define M_ 128
#define N_ 4096
#define S_ 32
#define ROWS (B_ * L_)          // 32768 rows of length N_

typedef __attribute__((ext_vector_type(8))) short    short8_t;   // 8 bf16 (4 VGPR)
typedef __attribute__((ext_vector_type(8))) unsigned short ushort8_t;
typedef __attribute__((ext_vector_type(4))) float    f32x4;
typedef __attribute__((ext_vector_type(4))) unsigned int uint4_t;

__device__ __forceinline__ unsigned short f2bf(float x) {  // RNE bf16
    unsigned u = __float_as_uint(x);
    unsigned r = (u + 0x7FFFu + ((u >> 16) & 1u)) >> 16;
    return (unsigned short)r;
}
__device__ __forceinline__ float bf2f(unsigned short h) {
    return __uint_as_float((unsigned)h << 16);
}

// 8-bit monotone magnitude key: 5-exp-binade window [2^-12, 16), 3 mantissa
// bits, truncating (one-sided <=6.25% relative underestimate).
#define KEY_E0 14720    // bf16-mag15 of 2^-12 (exp field 115 << 7)

// ---------------------------------------------------------------------------
// P0: PROLOGUE mega-kernel (block-range dispatch over independent jobs):
//   [0,2048)        zero LOW 8KB half of every y row (streaming writes)
//   [2048,10240)    prep_w: Wbf = bf16(We), cvec = b_d . We_n
//   [10240,26624)   prep_a: Abf = bf16(kin), layout [l][b][128]
//   [26624,26624+nT) transpose Wd -> WdT (only when WdT does NOT alias Wbf)
// ---------------------------------------------------------------------------
__global__ __launch_bounds__(256) void prologue(float* __restrict__ y,
                                                const float* __restrict__ We,
                                                const float* __restrict__ bd,
                                                unsigned short* __restrict__ Wbf,
                                                float* __restrict__ cvec,
                                                const float* __restrict__ kin,
                                                unsigned short* __restrict__ Abf,
                                                const float* __restrict__ Wd,
                                                float* __restrict__ WdT) {
    __shared__ float t[32][33];
    const int bid = blockIdx.x;
    const int tid = threadIdx.x;

    if (bid < 2048) {
        const float4 z = {0.f, 0.f, 0.f, 0.f};
        int idx = bid * 256 + tid;
        for (int i = idx; i < ROWS * 512; i += 2048 * 256) {
            int row = i >> 9, slot = i & 511;
            reinterpret_cast<float4*>(y + (size_t)row * N_)[slot] = z;
        }
    } else if (bid < 10240) {
        int wb = bid - 2048;
        int l = wb >> 8, nb = wb & 255;
        int nl = tid >> 4, tt = tid & 15;
        int n = nb * 16 + nl;
        const float* w = We + ((size_t)l * N_ + n) * M_ + tt * 8;
        const float* b = bd + l * M_ + tt * 8;
        float4 w0 = *(const float4*)(w), w1 = *(const float4*)(w + 4);
        float4 b0 = *(const float4*)(b), b1 = *(const float4*)(b + 4);
        ushort8_t o;
        o[0] = f2bf(w0.x); o[1] = f2bf(w0.y); o[2] = f2bf(w0.z); o[3] = f2bf(w0.w);
        o[4] = f2bf(w1.x); o[5] = f2bf(w1.y); o[6] = f2bf(w1.z); o[7] = f2bf(w1.w);
        *reinterpret_cast<ushort8_t*>(Wbf + ((size_t)l * N_ + n) * 128 + tt * 8) = o;
        float s = w0.x*b0.x + w0.y*b0.y + w0.z*b0.z + w0.w*b0.w
                + w1.x*b1.x + w1.y*b1.y + w1.z*b1.z + w1.w*b1.w;
        #pragma unroll
        for (int oo = 8; oo > 0; oo >>= 1) s += __shfl_xor(s, oo, 64);
        if (tt == 0) cvec[(size_t)l * N_ + n] = s;
    } else if (bid < 26624) {
        int g = (bid - 10240) * 256 + tid;        // over B*L*M
        int b = g >> 12, l = (g >> 7) & 31, m = g & 127;
        Abf[(((size_t)l * B_ + b) << 7) + m] = f2bf(kin[g]);
    } else {
        int tb = bid - 26624;
        int l  = tb >> 9;
        int rem = tb & 511;
        int n0 = (rem & 127) * 32, m0 = (rem >> 7) * 32;
        int tx = tid & 31, ty = tid >> 5;
        const float* src = Wd + (size_t)l * M_ * N_;
        for (int i = ty; i < 32; i += 8)
            t[i][tx] = src[(size_t)(m0 + i) * N_ + n0 + tx];
        __syncthreads();
        float* dst = WdT + (size_t)l * N_ * M_;
        for (int i = ty; i < 32; i += 8)
            dst[(size_t)(n0 + i) * M_ + m0 + tx] = t[tx][i];
    }
}

// ---------------------------------------------------------------------------
// K0: standalone transpose (fallback when WdT aliases Wbf)
// ---------------------------------------------------------------------------
__global__ __launch_bounds__(256) void transpose_wd(const float* __restrict__ Wd,
                                                    float* __restrict__ WdT) {
    __shared__ float t[32][33];
    int l = blockIdx.z;
    int n0 = blockIdx.x * 32, m0 = blockIdx.y * 32;
    int tx = threadIdx.x & 31, ty = threadIdx.x >> 5;
    const float* src = Wd + (size_t)l * M_ * N_;
    for (int i = ty; i < 32; i += 8)
        t[i][tx] = src[(size_t)(m0 + i) * N_ + n0 + tx];
    __syncthreads();
    float* dst = WdT + (size_t)l * N_ * M_;
    for (int i = ty; i < 32; i += 8)
        dst[(size_t)(n0 + i) * M_ + m0 + tx] = t[tx][i];
}

// ---------------------------------------------------------------------------
// K1: encoder approx GEMM via MFMA bf16, single term (K=128, 4 BK=32 steps).
// Chunked XCD swizzle (r18, measured -40us). Epilogue now emits 8-BIT
// magnitude KEYS (monotone, <=6.25% one-sided) into bytes [8KB,12KB) of each
// row's 16KB y slot -> approx traffic halved (134MB write + 134MB read).
// ---------------------------------------------------------------------------
__device__ __forceinline__ int swz(int row) { return (row & 3) ^ ((row >> 2) & 3); }

#define CPB 144   // byte-tile row pitch (128 data + 16 pad; 16B-aligned rows)

__global__ __launch_bounds__(256) void encoder_mfma(const unsigned short* __restrict__ Abf,
                                                    const unsigned short* __restrict__ Wbf,
                                                    const float* __restrict__ cvec,
                                                    unsigned char* __restrict__ y8) {
    const int orig = ((blockIdx.x & 7) << 10) + (blockIdx.x >> 3);
    const int l    = orig >> 8;                  // layer (4 per XCD chunk)
    const int rem  = orig & 255;
    const int bn0  = (rem & 31) * 128;           // n fastest
    const int bm0  = (rem >> 5) * 128;
    __shared__ __align__(16) unsigned char smemB[128 * CPB];   // 18KB
    unsigned short* As = (unsigned short*)smemB;               // 8KB staging
    unsigned short* Bs = (unsigned short*)(smemB + 8192);      // 8KB staging
    const int tid  = threadIdx.x;
    const int lane = tid & 63, wave = tid >> 6;
    const int wr = wave >> 1, wc = wave & 1;

    const unsigned short* Ab = Abf + (((size_t)l * B_ + bm0) << 7);
    const unsigned short* Wb = Wbf + (((size_t)l * N_ + bn0) << 7);

    auto stage = [&](int k0) {
        #pragma unroll
        for (int i = 0; i < 2; ++i) {
            int p   = i * 256 + tid;
            int row = p >> 2;
            int lc  = (p & 3) ^ swz(row);
            const unsigned short* g = Ab + ((size_t)row << 7) + k0 + lc * 8;
            unsigned dst = (unsigned)((i * 256 + (tid & ~63)) * 16);
            __builtin_amdgcn_global_load_lds(
                (const __attribute__((address_space(1))) void*)g,
                (__attribute__((address_space(3))) void*)((char*)As + dst), 16, 0, 0);
        }
        #pragma unroll
        for (int i = 0; i < 2; ++i) {
            int p   = i * 256 + tid;
            int row = p >> 2;
            int lc  = (p & 3) ^ swz(row);
            const unsigned short* g = Wb + ((size_t)row << 7) + k0 + lc * 8;
            unsigned dst = (unsigned)((i * 256 + (tid & ~63)) * 16);
            __builtin_amdgcn_global_load_lds(
                (const __attribute__((address_space(1))) void*)g,
                (__attribute__((address_space(3))) void*)((char*)Bs + dst), 16, 0, 0);
        }
    };

    f32x4 acc[4][4];
    #pragma unroll
    for (int i = 0; i < 4; ++i)
        #pragma unroll
        for (int j = 0; j < 4; ++j) acc[i][j] = (f32x4){0.f, 0.f, 0.f, 0.f};

    stage(0);
    __syncthreads();

    #pragma unroll
    for (int t = 0; t < 4; ++t) {
        short8_t aF[4], bF[4];
        const int kg = lane >> 4;
        #pragma unroll
        for (int mt = 0; mt < 4; ++mt) {
            int row = wr * 64 + mt * 16 + (lane & 15);
            int pc  = kg ^ swz(row);
            aF[mt] = *reinterpret_cast<const short8_t*>(As + row * 32 + pc * 8);
        }
        #pragma unroll
        for (int nt = 0; nt < 4; ++nt) {
            int row = wc * 64 + nt * 16 + (lane & 15);
            int pc  = kg ^ swz(row);
            bF[nt] = *reinterpret_cast<const short8_t*>(Bs + row * 32 + pc * 8);
        }
        #pragma unroll
        for (int mt = 0; mt < 4; ++mt)
            #pragma unroll
            for (int nt = 0; nt < 4; ++nt)
                acc[mt][nt] = __builtin_amdgcn_mfma_f32_16x16x32_bf16(
                    aF[mt], bF[nt], acc[mt][nt], 0, 0, 0);

        if (t < 3) {
            __syncthreads();
            stage((t + 1) * 32);
            __syncthreads();
        }
    }

    __syncthreads();   // staging dead; repurpose LDS as byte C tile

    #pragma unroll
    for (int nt = 0; nt < 4; ++nt) {
        int nl = wc * 64 + nt * 16 + (lane & 15);
        float cj = cvec[(size_t)l * N_ + bn0 + nl];
        #pragma unroll
        for (int mt = 0; mt < 4; ++mt) {
            #pragma unroll
            for (int j = 0; j < 4; ++j) {
                int rl = wr * 64 + mt * 16 + (lane >> 4) * 4 + j;
                float v = acc[mt][nt][j] - cj;
                unsigned mag = (__float_as_uint(v) >> 16) & 0x7FFFu;
                int key = ((int)mag - KEY_E0) >> 3;
                key = key < 0 ? 0 : (key > 255 ? 255 : key);
                smemB[rl * CPB + nl] = (unsigned char)key;
            }
        }
    }
    __syncthreads();

    // coalesced store: 1024 16B-chunks (128 rows x 128B); 4 per thread
    #pragma unroll
    for (int i = 0; i < 4; ++i) {
        int chunk = i * 256 + tid;
        int r = chunk >> 3, cch = chunk & 7;
        uint4_t v = *reinterpret_cast<const uint4_t*>(smemB + r * CPB + cch * 16);
        unsigned char* dst = y8 + ((size_t)((bm0 + r) * L_ + l)) * 16384 + 8192 + bn0 + cch * 16;
        *reinterpret_cast<uint4_t*>(dst) = v;
    }
}

// ---------------------------------------------------------------------------
// K2 (wave-per-row selector+decoder, zero block barriers).
// Front-end on 8-bit keys: 64B/lane (16 dwords), integer bisect on key space
// (<=8 steps, no moments), value-aware pool threshold key8(V(lo)-MARGIN)
// (provable superset of exact top-32; same margin constant validated r9-r19).
// Back-end unchanged: r4-verbatim exact recompute, exact rank, low scatter,
// fused decode. r19 reverse-recency row mapping kept.
// ---------------------------------------------------------------------------
#define POOL 128
#define MARGIN 1.2e-3f

__global__ __launch_bounds__(256) void topk_decode(float* __restrict__ y,
                                                   const float* __restrict__ We,
                                                   const float* __restrict__ WdT,
                                                   const float* __restrict__ kin,
                                                   const float* __restrict__ cvec,
                                                   int* __restrict__ cidx,
                                                   float* __restrict__ cval,
                                                   float* __restrict__ khat,
                                                   float* __restrict__ partial) {
    const int w    = threadIdx.x >> 6;          // wave id in block (0..3)
    const int lane = threadIdx.x & 63;
    const int i  = blockIdx.x;
    const int p  = 3 - (i >> 11);
    const int x  = (i >> 8) & 7;
    const int l  = 4 * x + p;
    const int j  = i & 255;
    const int bm = 7 - (j >> 5);
    const int bq = j & 31;
    const int b  = bm * 128 + bq * 4 + w;
    const int row = b * L_ + l;

    __shared__ __align__(16) float kinS[4][M_];
    __shared__ int   pidxS[4][POOL];
    __shared__ float pexS[4][POOL];
    __shared__ int   sidxS[4][S_];
    __shared__ float svalS[4][S_];

    float* yo = y + (size_t)row * N_;
    const unsigned char* ya8 = (const unsigned char*)y + (size_t)row * 16384 + 8192;

    kinS[w][lane]      = kin[(size_t)row * M_ + lane];
    kinS[w][lane + 64] = kin[(size_t)row * M_ + lane + 64];

    // load 64 key bytes (4 x 16B, coalesced: 64 lanes x 16B = 1KB/instr)
    unsigned ak[16];
    #pragma unroll
    for (int jj = 0; jj < 4; ++jj) {
        uint4_t q = *reinterpret_cast<const uint4_t*>(ya8 + jj * 1024 + lane * 16);
        #pragma unroll
        for (int d = 0; d < 4; ++d) ak[jj * 4 + d] = q[d];
    }

    // wave max key
    unsigned mxk = 0u;
    #pragma unroll
    for (int ii = 0; ii < 16; ++ii) {
        unsigned v = ak[ii];
        mxk = max(mxk, v & 0xFFu);
        mxk = max(mxk, (v >> 8) & 0xFFu);
        mxk = max(mxk, (v >> 16) & 0xFFu);
        mxk = max(mxk, v >> 24);
    }
    #pragma unroll
    for (int o = 32; o > 0; o >>= 1)
        mxk = max(mxk, (unsigned)__shfl_xor((int)mxk, o, 64));

    // integer bisect on 8-bit key space: invariant count(key >= lo) >= 32;
    // tighten until count <= 48 (or space exhausted; <= 12 iters bounded).
    unsigned lo = 0u, hi = mxk;
    int cl = N_;
    for (int it = 0; it < 12 && cl > 48 && lo < hi; ++it) {
        unsigned t = (it == 0) ? 121u : lo + ((hi - lo + 1u) >> 1);
        t = min(max(t, lo + 1u), hi);
        int c = 0;
        #pragma unroll
        for (int ii = 0; ii < 16; ++ii) {
            unsigned v = ak[ii];
            c += ((v & 0xFFu) >= t) ? 1 : 0;
            c += (((v >> 8) & 0xFFu) >= t) ? 1 : 0;
            c += (((v >> 16) & 0xFFu) >= t) ? 1 : 0;
            c += ((v >> 24) >= t) ? 1 : 0;
        }
        #pragma unroll
        for (int o = 32; o > 0; o >>= 1) c += __shfl_xor(c, o, 64);
        if (c >= S_) { lo = t; cl = c; } else { hi = t - 1u; }
    }

    // value-aware pool threshold: th = key8(max(V(lo) - MARGIN, 0)).
    // V(lo) = bucket floor; key8 truncation is monotone, so {key >= th} is a
    // superset of {|approx| >= V(lo) - MARGIN} which covers the exact top-32.
    const float lov = __uint_as_float((unsigned)(KEY_E0 + (int)(lo << 3)) << 16);
    const float thf = fmaxf(lov - MARGIN, 0.0f);
    int tht = ((int)((__float_as_uint(thf) >> 16) & 0x7FFFu) - KEY_E0) >> 3;
    const unsigned th = tht < 0 ? 0u : (unsigned)tht;

    // pool via ballot/scan compaction (no atomics)
    int myc = 0;
    #pragma unroll
    for (int ii = 0; ii < 16; ++ii) {
        unsigned v = ak[ii];
        myc += ((v & 0xFFu) >= th) ? 1 : 0;
        myc += (((v >> 8) & 0xFFu) >= th) ? 1 : 0;
        myc += (((v >> 16) & 0xFFu) >= th) ? 1 : 0;
        myc += ((v >> 24) >= th) ? 1 : 0;
    }
    int pos = myc;
    #pragma unroll
    for (int o = 1; o < 64; o <<= 1) {
        int t = __shfl_up(pos, o, 64);
        if (lane >= o) pos += t;
    }
    const int base  = pos - myc;                // exclusive prefix
    const int total = __shfl(pos, 63, 64);
    int k = 0;
    #pragma unroll
    for (int jj = 0; jj < 4; ++jj)
        #pragma unroll
        for (int d = 0; d < 4; ++d) {
            unsigned v = ak[jj * 4 + d];
            #pragma unroll
            for (int bb = 0; bb < 4; ++bb) {
                unsigned key = (v >> (bb * 8)) & 0xFFu;
                if (key >= th) {
                    int pp = base + k;
                    if (pp < POOL) pidxS[w][pp] = jj * 1024 + lane * 16 + d * 4 + bb;
                    ++k;
                }
            }
        }
    __asm__ __volatile__("s_waitcnt lgkmcnt(0)" ::: "memory");
    int c = total < POOL ? total : POOL;

    // exact recompute: STRICT ascending-m fmaf chain (bit-identical to r4);
    // float4 loads (We global L2-hot, kin LDS) then 4 in-order scalar fmafs.
    if (lane < c) {
        int n = pidxS[w][lane];
        const float4* wp4 = reinterpret_cast<const float4*>(We + ((size_t)l * N_ + n) * M_);
        const float4* kp4 = reinterpret_cast<const float4*>(kinS[w]);
        float acc = -cvec[(size_t)l * N_ + n];
        #pragma unroll 8
        for (int m4 = 0; m4 < 32; ++m4) {
            float4 wv = wp4[m4], kv = kp4[m4];
            acc = fmaf(wv.x, kv.x, acc);
            acc = fmaf(wv.y, kv.y, acc);
            acc = fmaf(wv.z, kv.z, acc);
            acc = fmaf(wv.w, kv.w, acc);
        }
        pexS[w][lane] = acc;
    }
    if (lane + 64 < c) {
        int n = pidxS[w][lane + 64];
        const float4* wp4 = reinterpret_cast<const float4*>(We + ((size_t)l * N_ + n) * M_);
        const float4* kp4 = reinterpret_cast<const float4*>(kinS[w]);
        float acc = -cvec[(size_t)l * N_ + n];
        #pragma unroll 8
        for (int m4 = 0; m4 < 32; ++m4) {
            float4 wv = wp4[m4], kv = kp4[m4];
            acc = fmaf(wv.x, kv.x, acc);
            acc = fmaf(wv.y, kv.y, acc);
            acc = fmaf(wv.z, kv.z, acc);
            acc = fmaf(wv.w, kv.w, acc);
        }
        pexS[w][lane + 64] = acc;
    }
    __asm__ __volatile__("s_waitcnt lgkmcnt(0)" ::: "memory");

    // exact rank (lowest-index tie-break); winners into LDS lists
    for (int e = lane; e < c; e += 64) {
        float ae = fabsf(pexS[w][e]);
        int   ne = pidxS[w][e];
        int rank = 0;
        for (int jj = 0; jj < c; ++jj) {
            float aj = fabsf(pexS[w][jj]);
            rank += ((aj > ae) || (aj == ae && pidxS[w][jj] < ne)) ? 1 : 0;
        }
        if (rank < S_) {
            sidxS[w][rank] = ne;
            svalS[w][rank] = pexS[w][e];
        }
    }
    __asm__ __volatile__("s_waitcnt lgkmcnt(0)" ::: "memory");

    // emit winner lists; DIRECT scatter of low-half winners
    if (lane < S_) {
        int n = sidxS[w][lane];
        float v = svalS[w][lane];
        cidx[(size_t)row * S_ + lane] = n;
        cval[(size_t)row * S_ + lane] = v;
        if (n < 2048) yo[n] = v;
    }

    // fused decode: 2 dims per lane; WdT rows L2-resident
    const float* wt = WdT + (size_t)l * N_ * M_;
    float acc0 = 0.0f, acc1 = 0.0f;
    #pragma unroll 8
    for (int jj = 0; jj < S_; ++jj) {
        float v = svalS[w][jj];
        const float* wrp = wt + (size_t)sidxS[w][jj] * M_;
        acc0 = fmaf(v, wrp[lane], acc0);
        acc1 = fmaf(v, wrp[lane + 64], acc1);
    }
    khat[(size_t)row * M_ + lane]      = acc0;
    khat[(size_t)row * M_ + lane + 64] = acc1;
    float r0 = acc0 - kinS[w][lane];
    float r1 = acc1 - kinS[w][lane + 64];
    float s = r0 * r0 + r1 * r1;
    #pragma unroll
    for (int o = 32; o > 0; o >>= 1) s += __shfl_xor(s, o, 64);
    if (lane == 0) partial[row] = s;
}

// ---------------------------------------------------------------------------
// K3: finish_high: zero the HIGH 8KB halves (covers the 4KB key region and
// the untouched 4KB above it) + scatter high winners, fused.
// ---------------------------------------------------------------------------
__global__ __launch_bounds__(256) void finish_high(float* __restrict__ y,
                                                   const int* __restrict__ cidx,
                                                   const float* __restrict__ cval) {
    const int bid = blockIdx.x;                 // 2048 blocks
    const int tid = threadIdx.x;
    const int row0 = bid * 16;
    const float4 z = {0.f, 0.f, 0.f, 0.f};
    #pragma unroll
    for (int i = 0; i < 32; ++i) {
        int g = i * 256 + tid;                  // 0..8191 float4s
        int r = row0 + (g >> 9);
        int slot = g & 511;
        reinterpret_cast<float4*>(y + (size_t)r * N_ + 2048)[slot] = z;
    }
    __syncthreads();    // vmcnt(0) drain before barrier
    #pragma unroll
    for (int i = 0; i < 2; ++i) {
        int e = i * 256 + tid;                  // 0..511 winner entries
        int g = row0 * S_ + e;
        int n = cidx[g];
        if (n >= 2048) {
            int r = row0 + (e >> 5);
            y[(size_t)r * N_ + n] = cval[g];
        }
    }
}

// ---------------------------------------------------------------------------
// K4: deterministic reduction of 32768 partials -> loss (float4 loads)
// ---------------------------------------------------------------------------
__global__ __launch_bounds__(256) void reduce_loss(const float* __restrict__ partial,
                                                   float* __restrict__ out_loss) {
    __shared__ float red[256];
    int tid = threadIdx.x;
    float s = 0.0f;
    for (int i = tid; i < ROWS / 4; i += 256) {
        float4 v = reinterpret_cast<const float4*>(partial)[i];
        s += v.x + v.y + v.z + v.w;
    }
    red[tid] = s;
    __syncthreads();
    for (int off = 128; off > 0; off >>= 1) {
        if (tid < off) red[tid] += red[tid + off];
        __syncthreads();
    }
    if (tid == 0) out_loss[0] = red[0] / (float)((size_t)B_ * L_ * M_);
}

// ---------------------------------------------------------------------------
extern "C" void kernel_launch(void* const* d_in, const int* in_sizes, int n_in,
                              void* d_out, int out_size, void* d_ws, size_t ws_size,
                              hipStream_t stream) {
    const float* kin = (const float*)d_in[0];   // [B][L][M]
    const float* We  = (const float*)d_in[1];   // [L][N][M]
    // d_in[2] = b_e (unused by reference encode())
    const float* Wd  = (const float*)d_in[3];   // [L][M][N]
    const float* bd  = (const float*)d_in[4];   // [L][M]
    // d_in[5] = s (==32, hardcoded)

    float* out   = (float*)d_out;
    float* loss  = out;                                   // [1]
    float* khat  = out + 1;                               // [B*L*M]
    float* y_out = out + 1 + (size_t)B_ * L_ * M_;        // [B*L*N]

    char* ws = (char*)d_ws;
    const bool wsBig = ws_size >= ((size_t)113u << 20);

    unsigned short* Wbf;
    unsigned short* Abf;
    int*   cidx;
    float* cval;
    float* cvec;
    float* partial;
    float* WdT;

    if (wsBig) {
        Wbf     = (unsigned short*)ws;                       // 0   .. 32 MiB
        Abf     = (unsigned short*)(ws + (32u << 20));       // 32  .. 40 MiB
        cidx    = (int*)  (ws + (40u << 20));                // 40  .. 44 MiB
        cval    = (float*)(ws + (44u << 20));                // 44  .. 48 MiB
        cvec    = (float*)(ws + (48u << 20));                // 48  .. 48.5 MiB
        partial = (float*)(ws + (48u << 20) + (512u << 10)); // 48.5.. 49 MiB
        WdT     = (float*)(ws + (49u << 20));                // 49  .. 113 MiB
    } else {
        Wbf     = (unsigned short*)ws;                       // 32 MiB
        Abf     = (unsigned short*)(ws + (64u << 20));       // 8 MiB
        cidx    = (int*)  (ws + (72u << 20));                // 4 MiB
        cval    = (float*)(ws + (76u << 20));                // 4 MiB
        cvec    = (float*)(ws + (80u << 20));                // 512 KiB
        partial = (float*)(ws + (81u << 20));                // 128 KiB
        WdT     = (float*)ws;                                // aliases Wbf
    }

    int nblocks = 26624 + (wsBig ? 16384 : 0);
    prologue<<<nblocks, 256, 0, stream>>>(y_out, We, bd, Wbf, cvec, kin, Abf, Wd, WdT);
    // encoder: 1-D grid, chunked XCD swizzle; emits 8-bit keys
    encoder_mfma<<<8192, 256, 0, stream>>>(Abf, Wbf, cvec, (unsigned char*)y_out);
    if (!wsBig)
        transpose_wd<<<dim3(N_ / 32, M_ / 32, L_), 256, 0, stream>>>(Wd, WdT);
    topk_decode<<<ROWS / 4, 256, 0, stream>>>(y_out, We, WdT, kin, cvec,
                                              cidx, cval, khat, partial);
    finish_high<<<2048, 256, 0, stream>>>(y_out, cidx, cval);
    reduce_loss<<<1, 256, 0, stream>>>(partial, loss);
}

// Round 21
// 527.190 us; speedup vs baseline: 1.1324x; 1.0216x over previous
//
#include <hip/hip_runtime.h>
#include <hip/hip_bf16.h>

// Problem constants (fixed by the reference)
#define B_ 1024
#define L_ 32
#define M_ 128
#define N_ 4096
#define S_ 32
#define ROWS (B_ * L_)          // 32768 rows of length N_

typedef __attribute__((ext_vector_type(8))) short    short8_t;   // 8 bf16 (4 VGPR)
typedef __attribute__((ext_vector_type(8))) unsigned short ushort8_t;
typedef __attribute__((ext_vector_type(4))) float    f32x4;
typedef __attribute__((ext_vector_type(4))) unsigned int uint4_t;

__device__ __forceinline__ unsigned short f2bf(float x) {  // RNE bf16
    unsigned u = __float_as_uint(x);
    unsigned r = (u + 0x7FFFu + ((u >> 16) & 1u)) >> 16;
    return (unsigned short)r;
}
__device__ __forceinline__ float bf2f(unsigned short h) {
    return __uint_as_float((unsigned)h << 16);
}

// 8-bit monotone magnitude key: 5-exp-binade window [2^-12, 16), 3 mantissa
// bits, truncating (one-sided <=6.25% relative underestimate).
#define KEY_E0 14720    // bf16-mag15 of 2^-12 (exp field 115 << 7)

// ---------------------------------------------------------------------------
// P0: PROLOGUE mega-kernel (block-range dispatch over independent jobs):
//   [0,2048)        zero LOW 8KB half of every y row (streaming writes)
//   [2048,10240)    prep_w: Wbf = bf16(We), cvec = b_d . We_n
//   [10240,26624)   prep_a: Abf = bf16(kin), layout [l][b][128]
//   [26624,26624+nT) transpose Wd -> WdT (only when WdT does NOT alias Wbf)
// ---------------------------------------------------------------------------
__global__ __launch_bounds__(256) void prologue(float* __restrict__ y,
                                                const float* __restrict__ We,
                                                const float* __restrict__ bd,
                                                unsigned short* __restrict__ Wbf,
                                                float* __restrict__ cvec,
                                                const float* __restrict__ kin,
                                                unsigned short* __restrict__ Abf,
                                                const float* __restrict__ Wd,
                                                float* __restrict__ WdT) {
    __shared__ float t[32][33];
    const int bid = blockIdx.x;
    const int tid = threadIdx.x;

    if (bid < 2048) {
        const float4 z = {0.f, 0.f, 0.f, 0.f};
        int idx = bid * 256 + tid;
        for (int i = idx; i < ROWS * 512; i += 2048 * 256) {
            int row = i >> 9, slot = i & 511;
            reinterpret_cast<float4*>(y + (size_t)row * N_)[slot] = z;
        }
    } else if (bid < 10240) {
        int wb = bid - 2048;
        int l = wb >> 8, nb = wb & 255;
        int nl = tid >> 4, tt = tid & 15;
        int n = nb * 16 + nl;
        const float* w = We + ((size_t)l * N_ + n) * M_ + tt * 8;
        const float* b = bd + l * M_ + tt * 8;
        float4 w0 = *(const float4*)(w), w1 = *(const float4*)(w + 4);
        float4 b0 = *(const float4*)(b), b1 = *(const float4*)(b + 4);
        ushort8_t o;
        o[0] = f2bf(w0.x); o[1] = f2bf(w0.y); o[2] = f2bf(w0.z); o[3] = f2bf(w0.w);
        o[4] = f2bf(w1.x); o[5] = f2bf(w1.y); o[6] = f2bf(w1.z); o[7] = f2bf(w1.w);
        *reinterpret_cast<ushort8_t*>(Wbf + ((size_t)l * N_ + n) * 128 + tt * 8) = o;
        float s = w0.x*b0.x + w0.y*b0.y + w0.z*b0.z + w0.w*b0.w
                + w1.x*b1.x + w1.y*b1.y + w1.z*b1.z + w1.w*b1.w;
        #pragma unroll
        for (int oo = 8; oo > 0; oo >>= 1) s += __shfl_xor(s, oo, 64);
        if (tt == 0) cvec[(size_t)l * N_ + n] = s;
    } else if (bid < 26624) {
        int g = (bid - 10240) * 256 + tid;        // over B*L*M
        int b = g >> 12, l = (g >> 7) & 31, m = g & 127;
        Abf[(((size_t)l * B_ + b) << 7) + m] = f2bf(kin[g]);
    } else {
        int tb = bid - 26624;
        int l  = tb >> 9;
        int rem = tb & 511;
        int n0 = (rem & 127) * 32, m0 = (rem >> 7) * 32;
        int tx = tid & 31, ty = tid >> 5;
        const float* src = Wd + (size_t)l * M_ * N_;
        for (int i = ty; i < 32; i += 8)
            t[i][tx] = src[(size_t)(m0 + i) * N_ + n0 + tx];
        __syncthreads();
        float* dst = WdT + (size_t)l * N_ * M_;
        for (int i = ty; i < 32; i += 8)
            dst[(size_t)(n0 + i) * M_ + m0 + tx] = t[tx][i];
    }
}

// ---------------------------------------------------------------------------
// K0: standalone transpose (fallback when WdT aliases Wbf)
// ---------------------------------------------------------------------------
__global__ __launch_bounds__(256) void transpose_wd(const float* __restrict__ Wd,
                                                    float* __restrict__ WdT) {
    __shared__ float t[32][33];
    int l = blockIdx.z;
    int n0 = blockIdx.x * 32, m0 = blockIdx.y * 32;
    int tx = threadIdx.x & 31, ty = threadIdx.x >> 5;
    const float* src = Wd + (size_t)l * M_ * N_;
    for (int i = ty; i < 32; i += 8)
        t[i][tx] = src[(size_t)(m0 + i) * N_ + n0 + tx];
    __syncthreads();
    float* dst = WdT + (size_t)l * N_ * M_;
    for (int i = ty; i < 32; i += 8)
        dst[(size_t)(n0 + i) * M_ + m0 + tx] = t[tx][i];
}

// ---------------------------------------------------------------------------
// K1: encoder approx GEMM via MFMA bf16, single term (K=128, 4 BK=32 steps).
// Chunked XCD swizzle (r18, measured -40us). Epilogue emits 8-bit magnitude
// keys into bytes [8KB,12KB) of each row's 16KB y slot.
// ---------------------------------------------------------------------------
__device__ __forceinline__ int swz(int row) { return (row & 3) ^ ((row >> 2) & 3); }

#define CPB 144   // byte-tile row pitch (128 data + 16 pad; 16B-aligned rows)

__global__ __launch_bounds__(256) void encoder_mfma(const unsigned short* __restrict__ Abf,
                                                    const unsigned short* __restrict__ Wbf,
                                                    const float* __restrict__ cvec,
                                                    unsigned char* __restrict__ y8) {
    const int orig = ((blockIdx.x & 7) << 10) + (blockIdx.x >> 3);
    const int l    = orig >> 8;                  // layer (4 per XCD chunk)
    const int rem  = orig & 255;
    const int bn0  = (rem & 31) * 128;           // n fastest
    const int bm0  = (rem >> 5) * 128;
    __shared__ __align__(16) unsigned char smemB[128 * CPB];   // 18KB
    unsigned short* As = (unsigned short*)smemB;               // 8KB staging
    unsigned short* Bs = (unsigned short*)(smemB + 8192);      // 8KB staging
    const int tid  = threadIdx.x;
    const int lane = tid & 63, wave = tid >> 6;
    const int wr = wave >> 1, wc = wave & 1;

    const unsigned short* Ab = Abf + (((size_t)l * B_ + bm0) << 7);
    const unsigned short* Wb = Wbf + (((size_t)l * N_ + bn0) << 7);

    auto stage = [&](int k0) {
        #pragma unroll
        for (int i = 0; i < 2; ++i) {
            int p   = i * 256 + tid;
            int row = p >> 2;
            int lc  = (p & 3) ^ swz(row);
            const unsigned short* g = Ab + ((size_t)row << 7) + k0 + lc * 8;
            unsigned dst = (unsigned)((i * 256 + (tid & ~63)) * 16);
            __builtin_amdgcn_global_load_lds(
                (const __attribute__((address_space(1))) void*)g,
                (__attribute__((address_space(3))) void*)((char*)As + dst), 16, 0, 0);
        }
        #pragma unroll
        for (int i = 0; i < 2; ++i) {
            int p   = i * 256 + tid;
            int row = p >> 2;
            int lc  = (p & 3) ^ swz(row);
            const unsigned short* g = Wb + ((size_t)row << 7) + k0 + lc * 8;
            unsigned dst = (unsigned)((i * 256 + (tid & ~63)) * 16);
            __builtin_amdgcn_global_load_lds(
                (const __attribute__((address_space(1))) void*)g,
                (__attribute__((address_space(3))) void*)((char*)Bs + dst), 16, 0, 0);
        }
    };

    f32x4 acc[4][4];
    #pragma unroll
    for (int i = 0; i < 4; ++i)
        #pragma unroll
        for (int j = 0; j < 4; ++j) acc[i][j] = (f32x4){0.f, 0.f, 0.f, 0.f};

    stage(0);
    __syncthreads();

    #pragma unroll
    for (int t = 0; t < 4; ++t) {
        short8_t aF[4], bF[4];
        const int kg = lane >> 4;
        #pragma unroll
        for (int mt = 0; mt < 4; ++mt) {
            int row = wr * 64 + mt * 16 + (lane & 15);
            int pc  = kg ^ swz(row);
            aF[mt] = *reinterpret_cast<const short8_t*>(As + row * 32 + pc * 8);
        }
        #pragma unroll
        for (int nt = 0; nt < 4; ++nt) {
            int row = wc * 64 + nt * 16 + (lane & 15);
            int pc  = kg ^ swz(row);
            bF[nt] = *reinterpret_cast<const short8_t*>(Bs + row * 32 + pc * 8);
        }
        #pragma unroll
        for (int mt = 0; mt < 4; ++mt)
            #pragma unroll
            for (int nt = 0; nt < 4; ++nt)
                acc[mt][nt] = __builtin_amdgcn_mfma_f32_16x16x32_bf16(
                    aF[mt], bF[nt], acc[mt][nt], 0, 0, 0);

        if (t < 3) {
            __syncthreads();
            stage((t + 1) * 32);
            __syncthreads();
        }
    }

    __syncthreads();   // staging dead; repurpose LDS as byte C tile

    #pragma unroll
    for (int nt = 0; nt < 4; ++nt) {
        int nl = wc * 64 + nt * 16 + (lane & 15);
        float cj = cvec[(size_t)l * N_ + bn0 + nl];
        #pragma unroll
        for (int mt = 0; mt < 4; ++mt) {
            #pragma unroll
            for (int j = 0; j < 4; ++j) {
                int rl = wr * 64 + mt * 16 + (lane >> 4) * 4 + j;
                float v = acc[mt][nt][j] - cj;
                unsigned mag = (__float_as_uint(v) >> 16) & 0x7FFFu;
                int key = ((int)mag - KEY_E0) >> 3;
                key = key < 0 ? 0 : (key > 255 ? 255 : key);
                smemB[rl * CPB + nl] = (unsigned char)key;
            }
        }
    }
    __syncthreads();

    // coalesced store: 1024 16B-chunks (128 rows x 128B); 4 per thread
    #pragma unroll
    for (int i = 0; i < 4; ++i) {
        int chunk = i * 256 + tid;
        int r = chunk >> 3, cch = chunk & 7;
        uint4_t v = *reinterpret_cast<const uint4_t*>(smemB + r * CPB + cch * 16);
        unsigned char* dst = y8 + ((size_t)((bm0 + r) * L_ + l)) * 16384 + 8192 + bn0 + cch * 16;
        *reinterpret_cast<uint4_t*>(dst) = v;
    }
}

// ---------------------------------------------------------------------------
// K2 (wave-per-row selector+decoder, zero block barriers) == r20 body with
// XCD-CHUNKED dispatch (r18's proven mechanism applied here): bid -> logical
// = (bid&7)*1024 + (bid>>3), so each XCD processes a contiguous run of 1024
// blocks = 4 layers sequentially; the per-layer We (2MB) + WdT (2MB) slices
// stay resident in THAT XCD's L2 instead of being replicated 8x and thrashed.
// Recency mapping on `logical` unchanged (r19).
// ---------------------------------------------------------------------------
#define POOL 128
#define MARGIN 1.2e-3f

__global__ __launch_bounds__(256) void topk_decode(float* __restrict__ y,
                                                   const float* __restrict__ We,
                                                   const float* __restrict__ WdT,
                                                   const float* __restrict__ kin,
                                                   const float* __restrict__ cvec,
                                                   int* __restrict__ cidx,
                                                   float* __restrict__ cval,
                                                   float* __restrict__ khat,
                                                   float* __restrict__ partial) {
    const int w    = threadIdx.x >> 6;          // wave id in block (0..3)
    const int lane = threadIdx.x & 63;
    // XCD-chunked dispatch, then recency mapping (bijective over 8192)
    const int i  = ((blockIdx.x & 7) << 10) + (blockIdx.x >> 3);
    const int p  = 3 - (i >> 11);
    const int x  = (i >> 8) & 7;
    const int l  = 4 * x + p;
    const int j  = i & 255;
    const int bm = 7 - (j >> 5);
    const int bq = j & 31;
    const int b  = bm * 128 + bq * 4 + w;
    const int row = b * L_ + l;

    __shared__ __align__(16) float kinS[4][M_];
    __shared__ int   pidxS[4][POOL];
    __shared__ float pexS[4][POOL];
    __shared__ int   sidxS[4][S_];
    __shared__ float svalS[4][S_];

    float* yo = y + (size_t)row * N_;
    const unsigned char* ya8 = (const unsigned char*)y + (size_t)row * 16384 + 8192;

    kinS[w][lane]      = kin[(size_t)row * M_ + lane];
    kinS[w][lane + 64] = kin[(size_t)row * M_ + lane + 64];

    // load 64 key bytes (4 x 16B, coalesced)
    unsigned ak[16];
    #pragma unroll
    for (int jj = 0; jj < 4; ++jj) {
        uint4_t q = *reinterpret_cast<const uint4_t*>(ya8 + jj * 1024 + lane * 16);
        #pragma unroll
        for (int d = 0; d < 4; ++d) ak[jj * 4 + d] = q[d];
    }

    // wave max key
    unsigned mxk = 0u;
    #pragma unroll
    for (int ii = 0; ii < 16; ++ii) {
        unsigned v = ak[ii];
        mxk = max(mxk, v & 0xFFu);
        mxk = max(mxk, (v >> 8) & 0xFFu);
        mxk = max(mxk, (v >> 16) & 0xFFu);
        mxk = max(mxk, v >> 24);
    }
    #pragma unroll
    for (int o = 32; o > 0; o >>= 1)
        mxk = max(mxk, (unsigned)__shfl_xor((int)mxk, o, 64));

    // integer bisect on 8-bit key space: invariant count(key >= lo) >= 32;
    // tighten until count <= 48.
    unsigned lo = 0u, hi = mxk;
    int cl = N_;
    for (int it = 0; it < 12 && cl > 48 && lo < hi; ++it) {
        unsigned t = (it == 0) ? 121u : lo + ((hi - lo + 1u) >> 1);
        t = min(max(t, lo + 1u), hi);
        int c = 0;
        #pragma unroll
        for (int ii = 0; ii < 16; ++ii) {
            unsigned v = ak[ii];
            c += ((v & 0xFFu) >= t) ? 1 : 0;
            c += (((v >> 8) & 0xFFu) >= t) ? 1 : 0;
            c += (((v >> 16) & 0xFFu) >= t) ? 1 : 0;
            c += ((v >> 24) >= t) ? 1 : 0;
        }
        #pragma unroll
        for (int o = 32; o > 0; o >>= 1) c += __shfl_xor(c, o, 64);
        if (c >= S_) { lo = t; cl = c; } else { hi = t - 1u; }
    }

    // value-aware pool threshold: th = key8(max(V(lo) - MARGIN, 0)).
    const float lov = __uint_as_float((unsigned)(KEY_E0 + (int)(lo << 3)) << 16);
    const float thf = fmaxf(lov - MARGIN, 0.0f);
    int tht = ((int)((__float_as_uint(thf) >> 16) & 0x7FFFu) - KEY_E0) >> 3;
    const unsigned th = tht < 0 ? 0u : (unsigned)tht;

    // pool via ballot/scan compaction (no atomics)
    int myc = 0;
    #pragma unroll
    for (int ii = 0; ii < 16; ++ii) {
        unsigned v = ak[ii];
        myc += ((v & 0xFFu) >= th) ? 1 : 0;
        myc += (((v >> 8) & 0xFFu) >= th) ? 1 : 0;
        myc += (((v >> 16) & 0xFFu) >= th) ? 1 : 0;
        myc += ((v >> 24) >= th) ? 1 : 0;
    }
    int pos = myc;
    #pragma unroll
    for (int o = 1; o < 64; o <<= 1) {
        int t = __shfl_up(pos, o, 64);
        if (lane >= o) pos += t;
    }
    const int base  = pos - myc;                // exclusive prefix
    const int total = __shfl(pos, 63, 64);
    int k = 0;
    #pragma unroll
    for (int jj = 0; jj < 4; ++jj)
        #pragma unroll
        for (int d = 0; d < 4; ++d) {
            unsigned v = ak[jj * 4 + d];
            #pragma unroll
            for (int bb = 0; bb < 4; ++bb) {
                unsigned key = (v >> (bb * 8)) & 0xFFu;
                if (key >= th) {
                    int pp = base + k;
                    if (pp < POOL) pidxS[w][pp] = jj * 1024 + lane * 16 + d * 4 + bb;
                    ++k;
                }
            }
        }
    __asm__ __volatile__("s_waitcnt lgkmcnt(0)" ::: "memory");
    int c = total < POOL ? total : POOL;

    // exact recompute: STRICT ascending-m fmaf chain (bit-identical to r4);
    // float4 loads (We global L2-hot, kin LDS) then 4 in-order scalar fmafs.
    if (lane < c) {
        int n = pidxS[w][lane];
        const float4* wp4 = reinterpret_cast<const float4*>(We + ((size_t)l * N_ + n) * M_);
        const float4* kp4 = reinterpret_cast<const float4*>(kinS[w]);
        float acc = -cvec[(size_t)l * N_ + n];
        #pragma unroll 8
        for (int m4 = 0; m4 < 32; ++m4) {
            float4 wv = wp4[m4], kv = kp4[m4];
            acc = fmaf(wv.x, kv.x, acc);
            acc = fmaf(wv.y, kv.y, acc);
            acc = fmaf(wv.z, kv.z, acc);
            acc = fmaf(wv.w, kv.w, acc);
        }
        pexS[w][lane] = acc;
    }
    if (lane + 64 < c) {
        int n = pidxS[w][lane + 64];
        const float4* wp4 = reinterpret_cast<const float4*>(We + ((size_t)l * N_ + n) * M_);
        const float4* kp4 = reinterpret_cast<const float4*>(kinS[w]);
        float acc = -cvec[(size_t)l * N_ + n];
        #pragma unroll 8
        for (int m4 = 0; m4 < 32; ++m4) {
            float4 wv = wp4[m4], kv = kp4[m4];
            acc = fmaf(wv.x, kv.x, acc);
            acc = fmaf(wv.y, kv.y, acc);
            acc = fmaf(wv.z, kv.z, acc);
            acc = fmaf(wv.w, kv.w, acc);
        }
        pexS[w][lane + 64] = acc;
    }
    __asm__ __volatile__("s_waitcnt lgkmcnt(0)" ::: "memory");

    // exact rank (lowest-index tie-break); winners into LDS lists
    for (int e = lane; e < c; e += 64) {
        float ae = fabsf(pexS[w][e]);
        int   ne = pidxS[w][e];
        int rank = 0;
        for (int jj = 0; jj < c; ++jj) {
            float aj = fabsf(pexS[w][jj]);
            rank += ((aj > ae) || (aj == ae && pidxS[w][jj] < ne)) ? 1 : 0;
        }
        if (rank < S_) {
            sidxS[w][rank] = ne;
            svalS[w][rank] = pexS[w][e];
        }
    }
    __asm__ __volatile__("s_waitcnt lgkmcnt(0)" ::: "memory");

    // emit winner lists; DIRECT scatter of low-half winners
    if (lane < S_) {
        int n = sidxS[w][lane];
        float v = svalS[w][lane];
        cidx[(size_t)row * S_ + lane] = n;
        cval[(size_t)row * S_ + lane] = v;
        if (n < 2048) yo[n] = v;
    }

    // fused decode: 2 dims per lane; WdT rows L2-resident (XCD-chunked)
    const float* wt = WdT + (size_t)l * N_ * M_;
    float acc0 = 0.0f, acc1 = 0.0f;
    #pragma unroll 8
    for (int jj = 0; jj < S_; ++jj) {
        float v = svalS[w][jj];
        const float* wrp = wt + (size_t)sidxS[w][jj] * M_;
        acc0 = fmaf(v, wrp[lane], acc0);
        acc1 = fmaf(v, wrp[lane + 64], acc1);
    }
    khat[(size_t)row * M_ + lane]      = acc0;
    khat[(size_t)row * M_ + lane + 64] = acc1;
    float r0 = acc0 - kinS[w][lane];
    float r1 = acc1 - kinS[w][lane + 64];
    float s = r0 * r0 + r1 * r1;
    #pragma unroll
    for (int o = 32; o > 0; o >>= 1) s += __shfl_xor(s, o, 64);
    if (lane == 0) partial[row] = s;
}

// ---------------------------------------------------------------------------
// K3: finish_high: zero the HIGH 8KB halves + scatter high winners, fused.
// Block 2048 additionally performs the loss reduction (partial[] is complete
// before this kernel launches).
// ---------------------------------------------------------------------------
__global__ __launch_bounds__(256) void finish_high(float* __restrict__ y,
                                                   const int* __restrict__ cidx,
                                                   const float* __restrict__ cval,
                                                   const float* __restrict__ partial,
                                                   float* __restrict__ out_loss) {
    const int bid = blockIdx.x;                 // 2049 blocks
    const int tid = threadIdx.x;
    if (bid == 2048) {
        // loss reduction (float4 loads)
        __shared__ float red[256];
        float s = 0.0f;
        for (int i = tid; i < ROWS / 4; i += 256) {
            float4 v = reinterpret_cast<const float4*>(partial)[i];
            s += v.x + v.y + v.z + v.w;
        }
        red[tid] = s;
        __syncthreads();
        for (int off = 128; off > 0; off >>= 1) {
            if (tid < off) red[tid] += red[tid + off];
            __syncthreads();
        }
        if (tid == 0) out_loss[0] = red[0] / (float)((size_t)B_ * L_ * M_);
        return;
    }
    const int row0 = bid * 16;
    const float4 z = {0.f, 0.f, 0.f, 0.f};
    #pragma unroll
    for (int i = 0; i < 32; ++i) {
        int g = i * 256 + tid;                  // 0..8191 float4s
        int r = row0 + (g >> 9);
        int slot = g & 511;
        reinterpret_cast<float4*>(y + (size_t)r * N_ + 2048)[slot] = z;
    }
    __syncthreads();    // vmcnt(0) drain before barrier
    #pragma unroll
    for (int i = 0; i < 2; ++i) {
        int e = i * 256 + tid;                  // 0..511 winner entries
        int g = row0 * S_ + e;
        int n = cidx[g];
        if (n >= 2048) {
            int r = row0 + (e >> 5);
            y[(size_t)r * N_ + n] = cval[g];
        }
    }
}

// ---------------------------------------------------------------------------
extern "C" void kernel_launch(void* const* d_in, const int* in_sizes, int n_in,
                              void* d_out, int out_size, void* d_ws, size_t ws_size,
                              hipStream_t stream) {
    const float* kin = (const float*)d_in[0];   // [B][L][M]
    const float* We  = (const float*)d_in[1];   // [L][N][M]
    // d_in[2] = b_e (unused by reference encode())
    const float* Wd  = (const float*)d_in[3];   // [L][M][N]
    const float* bd  = (const float*)d_in[4];   // [L][M]
    // d_in[5] = s (==32, hardcoded)

    float* out   = (float*)d_out;
    float* loss  = out;                                   // [1]
    float* khat  = out + 1;                               // [B*L*M]
    float* y_out = out + 1 + (size_t)B_ * L_ * M_;        // [B*L*N]

    char* ws = (char*)d_ws;
    const bool wsBig = ws_size >= ((size_t)113u << 20);

    unsigned short* Wbf;
    unsigned short* Abf;
    int*   cidx;
    float* cval;
    float* cvec;
    float* partial;
    float* WdT;

    if (wsBig) {
        Wbf     = (unsigned short*)ws;                       // 0   .. 32 MiB
        Abf     = (unsigned short*)(ws + (32u << 20));       // 32  .. 40 MiB
        cidx    = (int*)  (ws + (40u << 20));                // 40  .. 44 MiB
        cval    = (float*)(ws + (44u << 20));                // 44  .. 48 MiB
        cvec    = (float*)(ws + (48u << 20));                // 48  .. 48.5 MiB
        partial = (float*)(ws + (48u << 20) + (512u << 10)); // 48.5.. 49 MiB
        WdT     = (float*)(ws + (49u << 20));                // 49  .. 113 MiB
    } else {
        Wbf     = (unsigned short*)ws;                       // 32 MiB
        Abf     = (unsigned short*)(ws + (64u << 20));       // 8 MiB
        cidx    = (int*)  (ws + (72u << 20));                // 4 MiB
        cval    = (float*)(ws + (76u << 20));                // 4 MiB
        cvec    = (float*)(ws + (80u << 20));                // 512 KiB
        partial = (float*)(ws + (81u << 20));                // 128 KiB
        WdT     = (float*)ws;                                // aliases Wbf
    }

    int nblocks = 26624 + (wsBig ? 16384 : 0);
    prologue<<<nblocks, 256, 0, stream>>>(y_out, We, bd, Wbf, cvec, kin, Abf, Wd, WdT);
    // encoder: 1-D grid, chunked XCD swizzle; emits 8-bit keys
    encoder_mfma<<<8192, 256, 0, stream>>>(Abf, Wbf, cvec, (unsigned char*)y_out);
    if (!wsBig)
        transpose_wd<<<dim3(N_ / 32, M_ / 32, L_), 256, 0, stream>>>(Wd, WdT);
    // selector+decoder: XCD-chunked dispatch for We/WdT L2 residency
    topk_decode<<<ROWS / 4, 256, 0, stream>>>(y_out, We, WdT, kin, cvec,
                                              cidx, cval, khat, partial);
    // zero high halves + scatter high winners + loss reduction (fused)
    finish_high<<<2049, 256, 0, stream>>>(y_out, cidx, cval, partial, loss);
}

// Round 22
// 502.175 us; speedup vs baseline: 1.1888x; 1.0498x over previous
//
#include <hip/hip_runtime.h>
#include <hip/hip_bf16.h>

// Problem constants (fixed by the reference)
#define B_ 1024
#define L_ 32
#define M_ 128
#define N_ 4096
#define S_ 32
#define ROWS (B_ * L_)          // 32768 rows of length N_

typedef __attribute__((ext_vector_type(8))) short    short8_t;   // 8 bf16 (4 VGPR)
typedef __attribute__((ext_vector_type(8))) unsigned short ushort8_t;
typedef __attribute__((ext_vector_type(4))) float    f32x4;
typedef __attribute__((ext_vector_type(4))) unsigned int uint4_t;

__device__ __forceinline__ unsigned short f2bf(float x) {  // RNE bf16
    unsigned u = __float_as_uint(x);
    unsigned r = (u + 0x7FFFu + ((u >> 16) & 1u)) >> 16;
    return (unsigned short)r;
}
__device__ __forceinline__ float bf2f(unsigned short h) {
    return __uint_as_float((unsigned)h << 16);
}

// 8-bit monotone magnitude key: 5-exp-binade window [2^-12, 16), 3 mantissa
// bits, truncating (one-sided <=6.25% relative underestimate).
#define KEY_E0 14720    // bf16-mag15 of 2^-12 (exp field 115 << 7)

// ---------------------------------------------------------------------------
// P0: PROLOGUE mega-kernel (block-range dispatch over independent jobs):
//   [0,2048)        zero 3/4 of every y row slot: floats [0,2048) + [3072,4096)
//                   (keys occupy [2048,3072); that quarter is zeroed by finish)
//   [2048,10240)    prep_w: Wbf = bf16(We), cvec = b_d . We_n
//   [10240,26624)   prep_a: Abf = bf16(kin), layout [l][b][128]
//   [26624,26624+nT) transpose Wd -> WdT (only when WdT does NOT alias Wbf)
// ---------------------------------------------------------------------------
__global__ __launch_bounds__(256) void prologue(float* __restrict__ y,
                                                const float* __restrict__ We,
                                                const float* __restrict__ bd,
                                                unsigned short* __restrict__ Wbf,
                                                float* __restrict__ cvec,
                                                const float* __restrict__ kin,
                                                unsigned short* __restrict__ Abf,
                                                const float* __restrict__ Wd,
                                                float* __restrict__ WdT) {
    __shared__ float t[32][33];
    const int bid = blockIdx.x;
    const int tid = threadIdx.x;

    if (bid < 2048) {
        // 16 rows per block: zero low half (512 f4/row) + top quarter (256 f4/row)
        const int row0 = bid * 16;
        const float4 z = {0.f, 0.f, 0.f, 0.f};
        #pragma unroll
        for (int i = 0; i < 32; ++i) {
            int g = i * 256 + tid;              // 0..8191 over 16 rows x 512 f4
            int r = row0 + (g >> 9);
            int slot = g & 511;
            reinterpret_cast<float4*>(y + (size_t)r * N_)[slot] = z;
        }
        #pragma unroll
        for (int i = 0; i < 16; ++i) {
            int g = i * 256 + tid;              // 0..4095 over 16 rows x 256 f4
            int r = row0 + (g >> 8);
            int slot = g & 255;
            reinterpret_cast<float4*>(y + (size_t)r * N_ + 3072)[slot] = z;
        }
    } else if (bid < 10240) {
        int wb = bid - 2048;
        int l = wb >> 8, nb = wb & 255;
        int nl = tid >> 4, tt = tid & 15;
        int n = nb * 16 + nl;
        const float* w = We + ((size_t)l * N_ + n) * M_ + tt * 8;
        const float* b = bd + l * M_ + tt * 8;
        float4 w0 = *(const float4*)(w), w1 = *(const float4*)(w + 4);
        float4 b0 = *(const float4*)(b), b1 = *(const float4*)(b + 4);
        ushort8_t o;
        o[0] = f2bf(w0.x); o[1] = f2bf(w0.y); o[2] = f2bf(w0.z); o[3] = f2bf(w0.w);
        o[4] = f2bf(w1.x); o[5] = f2bf(w1.y); o[6] = f2bf(w1.z); o[7] = f2bf(w1.w);
        *reinterpret_cast<ushort8_t*>(Wbf + ((size_t)l * N_ + n) * 128 + tt * 8) = o;
        float s = w0.x*b0.x + w0.y*b0.y + w0.z*b0.z + w0.w*b0.w
                + w1.x*b1.x + w1.y*b1.y + w1.z*b1.z + w1.w*b1.w;
        #pragma unroll
        for (int oo = 8; oo > 0; oo >>= 1) s += __shfl_xor(s, oo, 64);
        if (tt == 0) cvec[(size_t)l * N_ + n] = s;
    } else if (bid < 26624) {
        int g = (bid - 10240) * 256 + tid;        // over B*L*M
        int b = g >> 12, l = (g >> 7) & 31, m = g & 127;
        Abf[(((size_t)l * B_ + b) << 7) + m] = f2bf(kin[g]);
    } else {
        int tb = bid - 26624;
        int l  = tb >> 9;
        int rem = tb & 511;
        int n0 = (rem & 127) * 32, m0 = (rem >> 7) * 32;
        int tx = tid & 31, ty = tid >> 5;
        const float* src = Wd + (size_t)l * M_ * N_;
        for (int i = ty; i < 32; i += 8)
            t[i][tx] = src[(size_t)(m0 + i) * N_ + n0 + tx];
        __syncthreads();
        float* dst = WdT + (size_t)l * N_ * M_;
        for (int i = ty; i < 32; i += 8)
            dst[(size_t)(n0 + i) * M_ + m0 + tx] = t[tx][i];
    }
}

// ---------------------------------------------------------------------------
// K0: standalone transpose (fallback when WdT aliases Wbf)
// ---------------------------------------------------------------------------
__global__ __launch_bounds__(256) void transpose_wd(const float* __restrict__ Wd,
                                                    float* __restrict__ WdT) {
    __shared__ float t[32][33];
    int l = blockIdx.z;
    int n0 = blockIdx.x * 32, m0 = blockIdx.y * 32;
    int tx = threadIdx.x & 31, ty = threadIdx.x >> 5;
    const float* src = Wd + (size_t)l * M_ * N_;
    for (int i = ty; i < 32; i += 8)
        t[i][tx] = src[(size_t)(m0 + i) * N_ + n0 + tx];
    __syncthreads();
    float* dst = WdT + (size_t)l * N_ * M_;
    for (int i = ty; i < 32; i += 8)
        dst[(size_t)(n0 + i) * M_ + m0 + tx] = t[tx][i];
}

// ---------------------------------------------------------------------------
// K1: encoder approx GEMM via MFMA bf16, single term (K=128, 4 BK=32 steps).
// Chunked XCD swizzle (r18). Epilogue emits 8-bit magnitude keys into bytes
// [8KB,12KB) of each row's 16KB y slot.
// ---------------------------------------------------------------------------
__device__ __forceinline__ int swz(int row) { return (row & 3) ^ ((row >> 2) & 3); }

#define CPB 144   // byte-tile row pitch (128 data + 16 pad; 16B-aligned rows)

__global__ __launch_bounds__(256) void encoder_mfma(const unsigned short* __restrict__ Abf,
                                                    const unsigned short* __restrict__ Wbf,
                                                    const float* __restrict__ cvec,
                                                    unsigned char* __restrict__ y8) {
    const int orig = ((blockIdx.x & 7) << 10) + (blockIdx.x >> 3);
    const int l    = orig >> 8;                  // layer (4 per XCD chunk)
    const int rem  = orig & 255;
    const int bn0  = (rem & 31) * 128;           // n fastest
    const int bm0  = (rem >> 5) * 128;
    __shared__ __align__(16) unsigned char smemB[128 * CPB];   // 18KB
    unsigned short* As = (unsigned short*)smemB;               // 8KB staging
    unsigned short* Bs = (unsigned short*)(smemB + 8192);      // 8KB staging
    const int tid  = threadIdx.x;
    const int lane = tid & 63, wave = tid >> 6;
    const int wr = wave >> 1, wc = wave & 1;

    const unsigned short* Ab = Abf + (((size_t)l * B_ + bm0) << 7);
    const unsigned short* Wb = Wbf + (((size_t)l * N_ + bn0) << 7);

    auto stage = [&](int k0) {
        #pragma unroll
        for (int i = 0; i < 2; ++i) {
            int p   = i * 256 + tid;
            int row = p >> 2;
            int lc  = (p & 3) ^ swz(row);
            const unsigned short* g = Ab + ((size_t)row << 7) + k0 + lc * 8;
            unsigned dst = (unsigned)((i * 256 + (tid & ~63)) * 16);
            __builtin_amdgcn_global_load_lds(
                (const __attribute__((address_space(1))) void*)g,
                (__attribute__((address_space(3))) void*)((char*)As + dst), 16, 0, 0);
        }
        #pragma unroll
        for (int i = 0; i < 2; ++i) {
            int p   = i * 256 + tid;
            int row = p >> 2;
            int lc  = (p & 3) ^ swz(row);
            const unsigned short* g = Wb + ((size_t)row << 7) + k0 + lc * 8;
            unsigned dst = (unsigned)((i * 256 + (tid & ~63)) * 16);
            __builtin_amdgcn_global_load_lds(
                (const __attribute__((address_space(1))) void*)g,
                (__attribute__((address_space(3))) void*)((char*)Bs + dst), 16, 0, 0);
        }
    };

    f32x4 acc[4][4];
    #pragma unroll
    for (int i = 0; i < 4; ++i)
        #pragma unroll
        for (int j = 0; j < 4; ++j) acc[i][j] = (f32x4){0.f, 0.f, 0.f, 0.f};

    stage(0);
    __syncthreads();

    #pragma unroll
    for (int t = 0; t < 4; ++t) {
        short8_t aF[4], bF[4];
        const int kg = lane >> 4;
        #pragma unroll
        for (int mt = 0; mt < 4; ++mt) {
            int row = wr * 64 + mt * 16 + (lane & 15);
            int pc  = kg ^ swz(row);
            aF[mt] = *reinterpret_cast<const short8_t*>(As + row * 32 + pc * 8);
        }
        #pragma unroll
        for (int nt = 0; nt < 4; ++nt) {
            int row = wc * 64 + nt * 16 + (lane & 15);
            int pc  = kg ^ swz(row);
            bF[nt] = *reinterpret_cast<const short8_t*>(Bs + row * 32 + pc * 8);
        }
        #pragma unroll
        for (int mt = 0; mt < 4; ++mt)
            #pragma unroll
            for (int nt = 0; nt < 4; ++nt)
                acc[mt][nt] = __builtin_amdgcn_mfma_f32_16x16x32_bf16(
                    aF[mt], bF[nt], acc[mt][nt], 0, 0, 0);

        if (t < 3) {
            __syncthreads();
            stage((t + 1) * 32);
            __syncthreads();
        }
    }

    __syncthreads();   // staging dead; repurpose LDS as byte C tile

    #pragma unroll
    for (int nt = 0; nt < 4; ++nt) {
        int nl = wc * 64 + nt * 16 + (lane & 15);
        float cj = cvec[(size_t)l * N_ + bn0 + nl];
        #pragma unroll
        for (int mt = 0; mt < 4; ++mt) {
            #pragma unroll
            for (int j = 0; j < 4; ++j) {
                int rl = wr * 64 + mt * 16 + (lane >> 4) * 4 + j;
                float v = acc[mt][nt][j] - cj;
                unsigned mag = (__float_as_uint(v) >> 16) & 0x7FFFu;
                int key = ((int)mag - KEY_E0) >> 3;
                key = key < 0 ? 0 : (key > 255 ? 255 : key);
                smemB[rl * CPB + nl] = (unsigned char)key;
            }
        }
    }
    __syncthreads();

    // coalesced store: 1024 16B-chunks (128 rows x 128B); 4 per thread
    #pragma unroll
    for (int i = 0; i < 4; ++i) {
        int chunk = i * 256 + tid;
        int r = chunk >> 3, cch = chunk & 7;
        uint4_t v = *reinterpret_cast<const uint4_t*>(smemB + r * CPB + cch * 16);
        unsigned char* dst = y8 + ((size_t)((bm0 + r) * L_ + l)) * 16384 + 8192 + bn0 + cch * 16;
        *reinterpret_cast<uint4_t*>(dst) = v;
    }
}

// ---------------------------------------------------------------------------
// K2 (wave-per-row selector+decoder, zero block barriers) == r21 body; direct
// scatter now covers n<2048 AND n>=3072 (both pre-zeroed by prologue); only
// winners inside the key quarter [2048,3072) defer to finish_high.
// ---------------------------------------------------------------------------
#define POOL 128
#define MARGIN 1.2e-3f

__global__ __launch_bounds__(256) void topk_decode(float* __restrict__ y,
                                                   const float* __restrict__ We,
                                                   const float* __restrict__ WdT,
                                                   const float* __restrict__ kin,
                                                   const float* __restrict__ cvec,
                                                   int* __restrict__ cidx,
                                                   float* __restrict__ cval,
                                                   float* __restrict__ khat,
                                                   float* __restrict__ partial) {
    const int w    = threadIdx.x >> 6;          // wave id in block (0..3)
    const int lane = threadIdx.x & 63;
    // XCD-chunked dispatch, then recency mapping (bijective over 8192)
    const int i  = ((blockIdx.x & 7) << 10) + (blockIdx.x >> 3);
    const int p  = 3 - (i >> 11);
    const int x  = (i >> 8) & 7;
    const int l  = 4 * x + p;
    const int j  = i & 255;
    const int bm = 7 - (j >> 5);
    const int bq = j & 31;
    const int b  = bm * 128 + bq * 4 + w;
    const int row = b * L_ + l;

    __shared__ __align__(16) float kinS[4][M_];
    __shared__ int   pidxS[4][POOL];
    __shared__ float pexS[4][POOL];
    __shared__ int   sidxS[4][S_];
    __shared__ float svalS[4][S_];

    float* yo = y + (size_t)row * N_;
    const unsigned char* ya8 = (const unsigned char*)y + (size_t)row * 16384 + 8192;

    kinS[w][lane]      = kin[(size_t)row * M_ + lane];
    kinS[w][lane + 64] = kin[(size_t)row * M_ + lane + 64];

    // load 64 key bytes (4 x 16B, coalesced)
    unsigned ak[16];
    #pragma unroll
    for (int jj = 0; jj < 4; ++jj) {
        uint4_t q = *reinterpret_cast<const uint4_t*>(ya8 + jj * 1024 + lane * 16);
        #pragma unroll
        for (int d = 0; d < 4; ++d) ak[jj * 4 + d] = q[d];
    }

    // wave max key
    unsigned mxk = 0u;
    #pragma unroll
    for (int ii = 0; ii < 16; ++ii) {
        unsigned v = ak[ii];
        mxk = max(mxk, v & 0xFFu);
        mxk = max(mxk, (v >> 8) & 0xFFu);
        mxk = max(mxk, (v >> 16) & 0xFFu);
        mxk = max(mxk, v >> 24);
    }
    #pragma unroll
    for (int o = 32; o > 0; o >>= 1)
        mxk = max(mxk, (unsigned)__shfl_xor((int)mxk, o, 64));

    // integer bisect on 8-bit key space: invariant count(key >= lo) >= 32;
    // tighten until count <= 48.
    unsigned lo = 0u, hi = mxk;
    int cl = N_;
    for (int it = 0; it < 12 && cl > 48 && lo < hi; ++it) {
        unsigned t = (it == 0) ? 121u : lo + ((hi - lo + 1u) >> 1);
        t = min(max(t, lo + 1u), hi);
        int c = 0;
        #pragma unroll
        for (int ii = 0; ii < 16; ++ii) {
            unsigned v = ak[ii];
            c += ((v & 0xFFu) >= t) ? 1 : 0;
            c += (((v >> 8) & 0xFFu) >= t) ? 1 : 0;
            c += (((v >> 16) & 0xFFu) >= t) ? 1 : 0;
            c += ((v >> 24) >= t) ? 1 : 0;
        }
        #pragma unroll
        for (int o = 32; o > 0; o >>= 1) c += __shfl_xor(c, o, 64);
        if (c >= S_) { lo = t; cl = c; } else { hi = t - 1u; }
    }

    // value-aware pool threshold: th = key8(max(V(lo) - MARGIN, 0)).
    const float lov = __uint_as_float((unsigned)(KEY_E0 + (int)(lo << 3)) << 16);
    const float thf = fmaxf(lov - MARGIN, 0.0f);
    int tht = ((int)((__float_as_uint(thf) >> 16) & 0x7FFFu) - KEY_E0) >> 3;
    const unsigned th = tht < 0 ? 0u : (unsigned)tht;

    // pool via ballot/scan compaction (no atomics)
    int myc = 0;
    #pragma unroll
    for (int ii = 0; ii < 16; ++ii) {
        unsigned v = ak[ii];
        myc += ((v & 0xFFu) >= th) ? 1 : 0;
        myc += (((v >> 8) & 0xFFu) >= th) ? 1 : 0;
        myc += (((v >> 16) & 0xFFu) >= th) ? 1 : 0;
        myc += ((v >> 24) >= th) ? 1 : 0;
    }
    int pos = myc;
    #pragma unroll
    for (int o = 1; o < 64; o <<= 1) {
        int t = __shfl_up(pos, o, 64);
        if (lane >= o) pos += t;
    }
    const int base  = pos - myc;                // exclusive prefix
    const int total = __shfl(pos, 63, 64);
    int k = 0;
    #pragma unroll
    for (int jj = 0; jj < 4; ++jj)
        #pragma unroll
        for (int d = 0; d < 4; ++d) {
            unsigned v = ak[jj * 4 + d];
            #pragma unroll
            for (int bb = 0; bb < 4; ++bb) {
                unsigned key = (v >> (bb * 8)) & 0xFFu;
                if (key >= th) {
                    int pp = base + k;
                    if (pp < POOL) pidxS[w][pp] = jj * 1024 + lane * 16 + d * 4 + bb;
                    ++k;
                }
            }
        }
    __asm__ __volatile__("s_waitcnt lgkmcnt(0)" ::: "memory");
    int c = total < POOL ? total : POOL;

    // exact recompute: STRICT ascending-m fmaf chain (bit-identical to r4);
    // float4 loads (We global L2-hot, kin LDS) then 4 in-order scalar fmafs.
    if (lane < c) {
        int n = pidxS[w][lane];
        const float4* wp4 = reinterpret_cast<const float4*>(We + ((size_t)l * N_ + n) * M_);
        const float4* kp4 = reinterpret_cast<const float4*>(kinS[w]);
        float acc = -cvec[(size_t)l * N_ + n];
        #pragma unroll 8
        for (int m4 = 0; m4 < 32; ++m4) {
            float4 wv = wp4[m4], kv = kp4[m4];
            acc = fmaf(wv.x, kv.x, acc);
            acc = fmaf(wv.y, kv.y, acc);
            acc = fmaf(wv.z, kv.z, acc);
            acc = fmaf(wv.w, kv.w, acc);
        }
        pexS[w][lane] = acc;
    }
    if (lane + 64 < c) {
        int n = pidxS[w][lane + 64];
        const float4* wp4 = reinterpret_cast<const float4*>(We + ((size_t)l * N_ + n) * M_);
        const float4* kp4 = reinterpret_cast<const float4*>(kinS[w]);
        float acc = -cvec[(size_t)l * N_ + n];
        #pragma unroll 8
        for (int m4 = 0; m4 < 32; ++m4) {
            float4 wv = wp4[m4], kv = kp4[m4];
            acc = fmaf(wv.x, kv.x, acc);
            acc = fmaf(wv.y, kv.y, acc);
            acc = fmaf(wv.z, kv.z, acc);
            acc = fmaf(wv.w, kv.w, acc);
        }
        pexS[w][lane + 64] = acc;
    }
    __asm__ __volatile__("s_waitcnt lgkmcnt(0)" ::: "memory");

    // exact rank (lowest-index tie-break); winners into LDS lists
    for (int e = lane; e < c; e += 64) {
        float ae = fabsf(pexS[w][e]);
        int   ne = pidxS[w][e];
        int rank = 0;
        for (int jj = 0; jj < c; ++jj) {
            float aj = fabsf(pexS[w][jj]);
            rank += ((aj > ae) || (aj == ae && pidxS[w][jj] < ne)) ? 1 : 0;
        }
        if (rank < S_) {
            sidxS[w][rank] = ne;
            svalS[w][rank] = pexS[w][e];
        }
    }
    __asm__ __volatile__("s_waitcnt lgkmcnt(0)" ::: "memory");

    // emit winner lists; DIRECT scatter outside the key quarter (pre-zeroed)
    if (lane < S_) {
        int n = sidxS[w][lane];
        float v = svalS[w][lane];
        cidx[(size_t)row * S_ + lane] = n;
        cval[(size_t)row * S_ + lane] = v;
        if (n < 2048 || n >= 3072) yo[n] = v;
    }

    // fused decode: 2 dims per lane; WdT rows L2-resident (XCD-chunked)
    const float* wt = WdT + (size_t)l * N_ * M_;
    float acc0 = 0.0f, acc1 = 0.0f;
    #pragma unroll 8
    for (int jj = 0; jj < S_; ++jj) {
        float v = svalS[w][jj];
        const float* wrp = wt + (size_t)sidxS[w][jj] * M_;
        acc0 = fmaf(v, wrp[lane], acc0);
        acc1 = fmaf(v, wrp[lane + 64], acc1);
    }
    khat[(size_t)row * M_ + lane]      = acc0;
    khat[(size_t)row * M_ + lane + 64] = acc1;
    float r0 = acc0 - kinS[w][lane];
    float r1 = acc1 - kinS[w][lane + 64];
    float s = r0 * r0 + r1 * r1;
    #pragma unroll
    for (int o = 32; o > 0; o >>= 1) s += __shfl_xor(s, o, 64);
    if (lane == 0) partial[row] = s;
}

// ---------------------------------------------------------------------------
// K3: finish_high: zero ONLY the key quarter (floats [2048,3072), 134MB) +
// scatter the winners that fall inside it. Block 2048 does the loss reduce.
// ---------------------------------------------------------------------------
__global__ __launch_bounds__(256) void finish_high(float* __restrict__ y,
                                                   const int* __restrict__ cidx,
                                                   const float* __restrict__ cval,
                                                   const float* __restrict__ partial,
                                                   float* __restrict__ out_loss) {
    const int bid = blockIdx.x;                 // 2049 blocks
    const int tid = threadIdx.x;
    if (bid == 2048) {
        __shared__ float red[256];
        float s = 0.0f;
        for (int i = tid; i < ROWS / 4; i += 256) {
            float4 v = reinterpret_cast<const float4*>(partial)[i];
            s += v.x + v.y + v.z + v.w;
        }
        red[tid] = s;
        __syncthreads();
        for (int off = 128; off > 0; off >>= 1) {
            if (tid < off) red[tid] += red[tid + off];
            __syncthreads();
        }
        if (tid == 0) out_loss[0] = red[0] / (float)((size_t)B_ * L_ * M_);
        return;
    }
    const int row0 = bid * 16;
    const float4 z = {0.f, 0.f, 0.f, 0.f};
    #pragma unroll
    for (int i = 0; i < 16; ++i) {
        int g = i * 256 + tid;                  // 0..4095 over 16 rows x 256 f4
        int r = row0 + (g >> 8);
        int slot = g & 255;
        reinterpret_cast<float4*>(y + (size_t)r * N_ + 2048)[slot] = z;
    }
    __syncthreads();    // vmcnt(0) drain before barrier
    #pragma unroll
    for (int i = 0; i < 2; ++i) {
        int e = i * 256 + tid;                  // 0..511 winner entries
        int g = row0 * S_ + e;
        int n = cidx[g];
        if (n >= 2048 && n < 3072) {
            int r = row0 + (e >> 5);
            y[(size_t)r * N_ + n] = cval[g];
        }
    }
}

// ---------------------------------------------------------------------------
extern "C" void kernel_launch(void* const* d_in, const int* in_sizes, int n_in,
                              void* d_out, int out_size, void* d_ws, size_t ws_size,
                              hipStream_t stream) {
    const float* kin = (const float*)d_in[0];   // [B][L][M]
    const float* We  = (const float*)d_in[1];   // [L][N][M]
    // d_in[2] = b_e (unused by reference encode())
    const float* Wd  = (const float*)d_in[3];   // [L][M][N]
    const float* bd  = (const float*)d_in[4];   // [L][M]
    // d_in[5] = s (==32, hardcoded)

    float* out   = (float*)d_out;
    float* loss  = out;                                   // [1]
    float* khat  = out + 1;                               // [B*L*M]
    float* y_out = out + 1 + (size_t)B_ * L_ * M_;        // [B*L*N]

    char* ws = (char*)d_ws;
    const bool wsBig = ws_size >= ((size_t)113u << 20);

    unsigned short* Wbf;
    unsigned short* Abf;
    int*   cidx;
    float* cval;
    float* cvec;
    float* partial;
    float* WdT;

    if (wsBig) {
        Wbf     = (unsigned short*)ws;                       // 0   .. 32 MiB
        Abf     = (unsigned short*)(ws + (32u << 20));       // 32  .. 40 MiB
        cidx    = (int*)  (ws + (40u << 20));                // 40  .. 44 MiB
        cval    = (float*)(ws + (44u << 20));                // 44  .. 48 MiB
        cvec    = (float*)(ws + (48u << 20));                // 48  .. 48.5 MiB
        partial = (float*)(ws + (48u << 20) + (512u << 10)); // 48.5.. 49 MiB
        WdT     = (float*)(ws + (49u << 20));                // 49  .. 113 MiB
    } else {
        Wbf     = (unsigned short*)ws;                       // 32 MiB
        Abf     = (unsigned short*)(ws + (64u << 20));       // 8 MiB
        cidx    = (int*)  (ws + (72u << 20));                // 4 MiB
        cval    = (float*)(ws + (76u << 20));                // 4 MiB
        cvec    = (float*)(ws + (80u << 20));                // 512 KiB
        partial = (float*)(ws + (81u << 20));                // 128 KiB
        WdT     = (float*)ws;                                // aliases Wbf
    }

    int nblocks = 26624 + (wsBig ? 16384 : 0);
    prologue<<<nblocks, 256, 0, stream>>>(y_out, We, bd, Wbf, cvec, kin, Abf, Wd, WdT);
    // encoder: 1-D grid, chunked XCD swizzle; emits 8-bit keys
    encoder_mfma<<<8192, 256, 0, stream>>>(Abf, Wbf, cvec, (unsigned char*)y_out);
    if (!wsBig)
        transpose_wd<<<dim3(N_ / 32, M_ / 32, L_), 256, 0, stream>>>(Wd, WdT);
    // selector+decoder: XCD-chunked dispatch for We/WdT L2 residency
    topk_decode<<<ROWS / 4, 256, 0, stream>>>(y_out, We, WdT, kin, cvec,
                                              cidx, cval, khat, partial);
    // zero key quarter + scatter its winners + loss reduction (fused)
    finish_high<<<2049, 256, 0, stream>>>(y_out, cidx, cval, partial, loss);
}

// Round 23
// 485.104 us; speedup vs baseline: 1.2306x; 1.0352x over previous
//
#include <hip/hip_runtime.h>
#include <hip/hip_bf16.h>

// Problem constants (fixed by the reference)
#define B_ 1024
#define L_ 32
#define M_ 128
#define N_ 4096
#define S_ 32
#define ROWS (B_ * L_)          // 32768 rows of length N_

typedef __attribute__((ext_vector_type(8))) short    short8_t;   // 8 bf16 (4 VGPR)
typedef __attribute__((ext_vector_type(8))) unsigned short ushort8_t;
typedef __attribute__((ext_vector_type(4))) float    f32x4;
typedef __attribute__((ext_vector_type(4))) unsigned int uint4_t;

__device__ __forceinline__ unsigned short f2bf(float x) {  // RNE bf16
    unsigned u = __float_as_uint(x);
    unsigned r = (u + 0x7FFFu + ((u >> 16) & 1u)) >> 16;
    return (unsigned short)r;
}
__device__ __forceinline__ float bf2f(unsigned short h) {
    return __uint_as_float((unsigned)h << 16);
}

// 8-bit monotone magnitude key: 5-exp-binade window [2^-12, 16), 3 mantissa
// bits, truncating (one-sided <=6.25% relative underestimate).
#define KEY_E0 14720    // bf16-mag15 of 2^-12 (exp field 115 << 7)

// ---------------------------------------------------------------------------
// P0: PROLOGUE mega-kernel (block-range dispatch over independent jobs):
//   [0,2048)        zero y rows: low half + top quarter always; key quarter
//                   too when fullZero (keys live in ws -> y fully pre-zeroed)
//   [2048,10240)    prep_w: Wbf = bf16(We), cvec = b_d . We_n
//   [10240,26624)   prep_a: Abf = bf16(kin), layout [l][b][128]
//   [26624,26624+nT) transpose Wd -> WdT (only when WdT does NOT alias Wbf)
// ---------------------------------------------------------------------------
__global__ __launch_bounds__(256) void prologue(float* __restrict__ y,
                                                const float* __restrict__ We,
                                                const float* __restrict__ bd,
                                                unsigned short* __restrict__ Wbf,
                                                float* __restrict__ cvec,
                                                const float* __restrict__ kin,
                                                unsigned short* __restrict__ Abf,
                                                const float* __restrict__ Wd,
                                                float* __restrict__ WdT,
                                                int fullZero) {
    __shared__ float t[32][33];
    const int bid = blockIdx.x;
    const int tid = threadIdx.x;

    if (bid < 2048) {
        const int row0 = bid * 16;
        const float4 z = {0.f, 0.f, 0.f, 0.f};
        #pragma unroll
        for (int i = 0; i < 32; ++i) {          // low half: 16 rows x 512 f4
            int g = i * 256 + tid;
            int r = row0 + (g >> 9);
            int slot = g & 511;
            reinterpret_cast<float4*>(y + (size_t)r * N_)[slot] = z;
        }
        #pragma unroll
        for (int i = 0; i < 16; ++i) {          // top quarter: 16 rows x 256 f4
            int g = i * 256 + tid;
            int r = row0 + (g >> 8);
            int slot = g & 255;
            reinterpret_cast<float4*>(y + (size_t)r * N_ + 3072)[slot] = z;
        }
        if (fullZero) {
            #pragma unroll
            for (int i = 0; i < 16; ++i) {      // key quarter: 16 rows x 256 f4
                int g = i * 256 + tid;
                int r = row0 + (g >> 8);
                int slot = g & 255;
                reinterpret_cast<float4*>(y + (size_t)r * N_ + 2048)[slot] = z;
            }
        }
    } else if (bid < 10240) {
        int wb = bid - 2048;
        int l = wb >> 8, nb = wb & 255;
        int nl = tid >> 4, tt = tid & 15;
        int n = nb * 16 + nl;
        const float* w = We + ((size_t)l * N_ + n) * M_ + tt * 8;
        const float* b = bd + l * M_ + tt * 8;
        float4 w0 = *(const float4*)(w), w1 = *(const float4*)(w + 4);
        float4 b0 = *(const float4*)(b), b1 = *(const float4*)(b + 4);
        ushort8_t o;
        o[0] = f2bf(w0.x); o[1] = f2bf(w0.y); o[2] = f2bf(w0.z); o[3] = f2bf(w0.w);
        o[4] = f2bf(w1.x); o[5] = f2bf(w1.y); o[6] = f2bf(w1.z); o[7] = f2bf(w1.w);
        *reinterpret_cast<ushort8_t*>(Wbf + ((size_t)l * N_ + n) * 128 + tt * 8) = o;
        float s = w0.x*b0.x + w0.y*b0.y + w0.z*b0.z + w0.w*b0.w
                + w1.x*b1.x + w1.y*b1.y + w1.z*b1.z + w1.w*b1.w;
        #pragma unroll
        for (int oo = 8; oo > 0; oo >>= 1) s += __shfl_xor(s, oo, 64);
        if (tt == 0) cvec[(size_t)l * N_ + n] = s;
    } else if (bid < 26624) {
        int g = (bid - 10240) * 256 + tid;        // over B*L*M
        int b = g >> 12, l = (g >> 7) & 31, m = g & 127;
        Abf[(((size_t)l * B_ + b) << 7) + m] = f2bf(kin[g]);
    } else {
        int tb = bid - 26624;
        int l  = tb >> 9;
        int rem = tb & 511;
        int n0 = (rem & 127) * 32, m0 = (rem >> 7) * 32;
        int tx = tid & 31, ty = tid >> 5;
        const float* src = Wd + (size_t)l * M_ * N_;
        for (int i = ty; i < 32; i += 8)
            t[i][tx] = src[(size_t)(m0 + i) * N_ + n0 + tx];
        __syncthreads();
        float* dst = WdT + (size_t)l * N_ * M_;
        for (int i = ty; i < 32; i += 8)
            dst[(size_t)(n0 + i) * M_ + m0 + tx] = t[tx][i];
    }
}

// ---------------------------------------------------------------------------
// K0: standalone transpose (fallback when WdT aliases Wbf)
// ---------------------------------------------------------------------------
__global__ __launch_bounds__(256) void transpose_wd(const float* __restrict__ Wd,
                                                    float* __restrict__ WdT) {
    __shared__ float t[32][33];
    int l = blockIdx.z;
    int n0 = blockIdx.x * 32, m0 = blockIdx.y * 32;
    int tx = threadIdx.x & 31, ty = threadIdx.x >> 5;
    const float* src = Wd + (size_t)l * M_ * N_;
    for (int i = ty; i < 32; i += 8)
        t[i][tx] = src[(size_t)(m0 + i) * N_ + n0 + tx];
    __syncthreads();
    float* dst = WdT + (size_t)l * N_ * M_;
    for (int i = ty; i < 32; i += 8)
        dst[(size_t)(n0 + i) * M_ + m0 + tx] = t[tx][i];
}

// ---------------------------------------------------------------------------
// K1: encoder approx GEMM via MFMA bf16, single term (K=128, 4 BK=32 steps).
// Chunked XCD swizzle (r18). Epilogue emits 8-bit magnitude keys to
// kbase + row*kstride + koff (in-y: 16384/8192; in-ws: 4096/0).
// ---------------------------------------------------------------------------
__device__ __forceinline__ int swz(int row) { return (row & 3) ^ ((row >> 2) & 3); }

#define CPB 144   // byte-tile row pitch (128 data + 16 pad; 16B-aligned rows)

__global__ __launch_bounds__(256) void encoder_mfma(const unsigned short* __restrict__ Abf,
                                                    const unsigned short* __restrict__ Wbf,
                                                    const float* __restrict__ cvec,
                                                    unsigned char* __restrict__ kbase,
                                                    int kstride, int koff) {
    const int orig = ((blockIdx.x & 7) << 10) + (blockIdx.x >> 3);
    const int l    = orig >> 8;                  // layer (4 per XCD chunk)
    const int rem  = orig & 255;
    const int bn0  = (rem & 31) * 128;           // n fastest
    const int bm0  = (rem >> 5) * 128;
    __shared__ __align__(16) unsigned char smemB[128 * CPB];   // 18KB
    unsigned short* As = (unsigned short*)smemB;               // 8KB staging
    unsigned short* Bs = (unsigned short*)(smemB + 8192);      // 8KB staging
    const int tid  = threadIdx.x;
    const int lane = tid & 63, wave = tid >> 6;
    const int wr = wave >> 1, wc = wave & 1;

    const unsigned short* Ab = Abf + (((size_t)l * B_ + bm0) << 7);
    const unsigned short* Wb = Wbf + (((size_t)l * N_ + bn0) << 7);

    auto stage = [&](int k0) {
        #pragma unroll
        for (int i = 0; i < 2; ++i) {
            int p   = i * 256 + tid;
            int row = p >> 2;
            int lc  = (p & 3) ^ swz(row);
            const unsigned short* g = Ab + ((size_t)row << 7) + k0 + lc * 8;
            unsigned dst = (unsigned)((i * 256 + (tid & ~63)) * 16);
            __builtin_amdgcn_global_load_lds(
                (const __attribute__((address_space(1))) void*)g,
                (__attribute__((address_space(3))) void*)((char*)As + dst), 16, 0, 0);
        }
        #pragma unroll
        for (int i = 0; i < 2; ++i) {
            int p   = i * 256 + tid;
            int row = p >> 2;
            int lc  = (p & 3) ^ swz(row);
            const unsigned short* g = Wb + ((size_t)row << 7) + k0 + lc * 8;
            unsigned dst = (unsigned)((i * 256 + (tid & ~63)) * 16);
            __builtin_amdgcn_global_load_lds(
                (const __attribute__((address_space(1))) void*)g,
                (__attribute__((address_space(3))) void*)((char*)Bs + dst), 16, 0, 0);
        }
    };

    f32x4 acc[4][4];
    #pragma unroll
    for (int i = 0; i < 4; ++i)
        #pragma unroll
        for (int j = 0; j < 4; ++j) acc[i][j] = (f32x4){0.f, 0.f, 0.f, 0.f};

    stage(0);
    __syncthreads();

    #pragma unroll
    for (int t = 0; t < 4; ++t) {
        short8_t aF[4], bF[4];
        const int kg = lane >> 4;
        #pragma unroll
        for (int mt = 0; mt < 4; ++mt) {
            int row = wr * 64 + mt * 16 + (lane & 15);
            int pc  = kg ^ swz(row);
            aF[mt] = *reinterpret_cast<const short8_t*>(As + row * 32 + pc * 8);
        }
        #pragma unroll
        for (int nt = 0; nt < 4; ++nt) {
            int row = wc * 64 + nt * 16 + (lane & 15);
            int pc  = kg ^ swz(row);
            bF[nt] = *reinterpret_cast<const short8_t*>(Bs + row * 32 + pc * 8);
        }
        #pragma unroll
        for (int mt = 0; mt < 4; ++mt)
            #pragma unroll
            for (int nt = 0; nt < 4; ++nt)
                acc[mt][nt] = __builtin_amdgcn_mfma_f32_16x16x32_bf16(
                    aF[mt], bF[nt], acc[mt][nt], 0, 0, 0);

        if (t < 3) {
            __syncthreads();
            stage((t + 1) * 32);
            __syncthreads();
        }
    }

    __syncthreads();   // staging dead; repurpose LDS as byte C tile

    #pragma unroll
    for (int nt = 0; nt < 4; ++nt) {
        int nl = wc * 64 + nt * 16 + (lane & 15);
        float cj = cvec[(size_t)l * N_ + bn0 + nl];
        #pragma unroll
        for (int mt = 0; mt < 4; ++mt) {
            #pragma unroll
            for (int j = 0; j < 4; ++j) {
                int rl = wr * 64 + mt * 16 + (lane >> 4) * 4 + j;
                float v = acc[mt][nt][j] - cj;
                unsigned mag = (__float_as_uint(v) >> 16) & 0x7FFFu;
                int key = ((int)mag - KEY_E0) >> 3;
                key = key < 0 ? 0 : (key > 255 ? 255 : key);
                smemB[rl * CPB + nl] = (unsigned char)key;
            }
        }
    }
    __syncthreads();

    // coalesced store: 1024 16B-chunks (128 rows x 128B); 4 per thread
    #pragma unroll
    for (int i = 0; i < 4; ++i) {
        int chunk = i * 256 + tid;
        int r = chunk >> 3, cch = chunk & 7;
        uint4_t v = *reinterpret_cast<const uint4_t*>(smemB + r * CPB + cch * 16);
        unsigned char* dst = kbase + (size_t)((bm0 + r) * L_ + l) * kstride + koff + bn0 + cch * 16;
        *reinterpret_cast<uint4_t*>(dst) = v;
    }
}

// ---------------------------------------------------------------------------
// K2 (wave-per-row selector+decoder, zero block barriers) == r22 body with
// parametrized key source and scatter predicate: winners with n in [loQ,hiQ)
// defer to finish_high (in-ws mode: loQ=hiQ=0 -> all winners scatter direct).
// ---------------------------------------------------------------------------
#define POOL 128
#define MARGIN 1.2e-3f

__global__ __launch_bounds__(256) void topk_decode(float* __restrict__ y,
                                                   const unsigned char* __restrict__ kbase,
                                                   int kstride, int koff,
                                                   int loQ, int hiQ,
                                                   const float* __restrict__ We,
                                                   const float* __restrict__ WdT,
                                                   const float* __restrict__ kin,
                                                   const float* __restrict__ cvec,
                                                   int* __restrict__ cidx,
                                                   float* __restrict__ cval,
                                                   float* __restrict__ khat,
                                                   float* __restrict__ partial) {
    const int w    = threadIdx.x >> 6;          // wave id in block (0..3)
    const int lane = threadIdx.x & 63;
    // XCD-chunked dispatch, then recency mapping (bijective over 8192)
    const int i  = ((blockIdx.x & 7) << 10) + (blockIdx.x >> 3);
    const int p  = 3 - (i >> 11);
    const int x  = (i >> 8) & 7;
    const int l  = 4 * x + p;
    const int j  = i & 255;
    const int bm = 7 - (j >> 5);
    const int bq = j & 31;
    const int b  = bm * 128 + bq * 4 + w;
    const int row = b * L_ + l;

    __shared__ __align__(16) float kinS[4][M_];
    __shared__ int   pidxS[4][POOL];
    __shared__ float pexS[4][POOL];
    __shared__ int   sidxS[4][S_];
    __shared__ float svalS[4][S_];

    float* yo = y + (size_t)row * N_;
    const unsigned char* ya8 = kbase + (size_t)row * kstride + koff;

    kinS[w][lane]      = kin[(size_t)row * M_ + lane];
    kinS[w][lane + 64] = kin[(size_t)row * M_ + lane + 64];

    // load 64 key bytes (4 x 16B, coalesced)
    unsigned ak[16];
    #pragma unroll
    for (int jj = 0; jj < 4; ++jj) {
        uint4_t q = *reinterpret_cast<const uint4_t*>(ya8 + jj * 1024 + lane * 16);
        #pragma unroll
        for (int d = 0; d < 4; ++d) ak[jj * 4 + d] = q[d];
    }

    // wave max key
    unsigned mxk = 0u;
    #pragma unroll
    for (int ii = 0; ii < 16; ++ii) {
        unsigned v = ak[ii];
        mxk = max(mxk, v & 0xFFu);
        mxk = max(mxk, (v >> 8) & 0xFFu);
        mxk = max(mxk, (v >> 16) & 0xFFu);
        mxk = max(mxk, v >> 24);
    }
    #pragma unroll
    for (int o = 32; o > 0; o >>= 1)
        mxk = max(mxk, (unsigned)__shfl_xor((int)mxk, o, 64));

    // integer bisect on 8-bit key space: invariant count(key >= lo) >= 32;
    // tighten until count <= 48.
    unsigned lo = 0u, hi = mxk;
    int cl = N_;
    for (int it = 0; it < 12 && cl > 48 && lo < hi; ++it) {
        unsigned t = (it == 0) ? 121u : lo + ((hi - lo + 1u) >> 1);
        t = min(max(t, lo + 1u), hi);
        int c = 0;
        #pragma unroll
        for (int ii = 0; ii < 16; ++ii) {
            unsigned v = ak[ii];
            c += ((v & 0xFFu) >= t) ? 1 : 0;
            c += (((v >> 8) & 0xFFu) >= t) ? 1 : 0;
            c += (((v >> 16) & 0xFFu) >= t) ? 1 : 0;
            c += ((v >> 24) >= t) ? 1 : 0;
        }
        #pragma unroll
        for (int o = 32; o > 0; o >>= 1) c += __shfl_xor(c, o, 64);
        if (c >= S_) { lo = t; cl = c; } else { hi = t - 1u; }
    }

    // value-aware pool threshold: th = key8(max(V(lo) - MARGIN, 0)).
    const float lov = __uint_as_float((unsigned)(KEY_E0 + (int)(lo << 3)) << 16);
    const float thf = fmaxf(lov - MARGIN, 0.0f);
    int tht = ((int)((__float_as_uint(thf) >> 16) & 0x7FFFu) - KEY_E0) >> 3;
    const unsigned th = tht < 0 ? 0u : (unsigned)tht;

    // pool via ballot/scan compaction (no atomics)
    int myc = 0;
    #pragma unroll
    for (int ii = 0; ii < 16; ++ii) {
        unsigned v = ak[ii];
        myc += ((v & 0xFFu) >= th) ? 1 : 0;
        myc += (((v >> 8) & 0xFFu) >= th) ? 1 : 0;
        myc += (((v >> 16) & 0xFFu) >= th) ? 1 : 0;
        myc += ((v >> 24) >= th) ? 1 : 0;
    }
    int pos = myc;
    #pragma unroll
    for (int o = 1; o < 64; o <<= 1) {
        int t = __shfl_up(pos, o, 64);
        if (lane >= o) pos += t;
    }
    const int base  = pos - myc;                // exclusive prefix
    const int total = __shfl(pos, 63, 64);
    int k = 0;
    #pragma unroll
    for (int jj = 0; jj < 4; ++jj)
        #pragma unroll
        for (int d = 0; d < 4; ++d) {
            unsigned v = ak[jj * 4 + d];
            #pragma unroll
            for (int bb = 0; bb < 4; ++bb) {
                unsigned key = (v >> (bb * 8)) & 0xFFu;
                if (key >= th) {
                    int pp = base + k;
                    if (pp < POOL) pidxS[w][pp] = jj * 1024 + lane * 16 + d * 4 + bb;
                    ++k;
                }
            }
        }
    __asm__ __volatile__("s_waitcnt lgkmcnt(0)" ::: "memory");
    int c = total < POOL ? total : POOL;

    // exact recompute: STRICT ascending-m fmaf chain (bit-identical to r4);
    // float4 loads (We global L2-hot, kin LDS) then 4 in-order scalar fmafs.
    if (lane < c) {
        int n = pidxS[w][lane];
        const float4* wp4 = reinterpret_cast<const float4*>(We + ((size_t)l * N_ + n) * M_);
        const float4* kp4 = reinterpret_cast<const float4*>(kinS[w]);
        float acc = -cvec[(size_t)l * N_ + n];
        #pragma unroll 8
        for (int m4 = 0; m4 < 32; ++m4) {
            float4 wv = wp4[m4], kv = kp4[m4];
            acc = fmaf(wv.x, kv.x, acc);
            acc = fmaf(wv.y, kv.y, acc);
            acc = fmaf(wv.z, kv.z, acc);
            acc = fmaf(wv.w, kv.w, acc);
        }
        pexS[w][lane] = acc;
    }
    if (lane + 64 < c) {
        int n = pidxS[w][lane + 64];
        const float4* wp4 = reinterpret_cast<const float4*>(We + ((size_t)l * N_ + n) * M_);
        const float4* kp4 = reinterpret_cast<const float4*>(kinS[w]);
        float acc = -cvec[(size_t)l * N_ + n];
        #pragma unroll 8
        for (int m4 = 0; m4 < 32; ++m4) {
            float4 wv = wp4[m4], kv = kp4[m4];
            acc = fmaf(wv.x, kv.x, acc);
            acc = fmaf(wv.y, kv.y, acc);
            acc = fmaf(wv.z, kv.z, acc);
            acc = fmaf(wv.w, kv.w, acc);
        }
        pexS[w][lane + 64] = acc;
    }
    __asm__ __volatile__("s_waitcnt lgkmcnt(0)" ::: "memory");

    // exact rank (lowest-index tie-break); winners into LDS lists
    for (int e = lane; e < c; e += 64) {
        float ae = fabsf(pexS[w][e]);
        int   ne = pidxS[w][e];
        int rank = 0;
        for (int jj = 0; jj < c; ++jj) {
            float aj = fabsf(pexS[w][jj]);
            rank += ((aj > ae) || (aj == ae && pidxS[w][jj] < ne)) ? 1 : 0;
        }
        if (rank < S_) {
            sidxS[w][rank] = ne;
            svalS[w][rank] = pexS[w][e];
        }
    }
    __asm__ __volatile__("s_waitcnt lgkmcnt(0)" ::: "memory");

    // emit winner lists; DIRECT scatter outside [loQ,hiQ) (pre-zeroed region)
    if (lane < S_) {
        int n = sidxS[w][lane];
        float v = svalS[w][lane];
        cidx[(size_t)row * S_ + lane] = n;
        cval[(size_t)row * S_ + lane] = v;
        if (n < loQ || n >= hiQ) yo[n] = v;
    }

    // fused decode: 2 dims per lane; WdT rows L2-resident (XCD-chunked)
    const float* wt = WdT + (size_t)l * N_ * M_;
    float acc0 = 0.0f, acc1 = 0.0f;
    #pragma unroll 8
    for (int jj = 0; jj < S_; ++jj) {
        float v = svalS[w][jj];
        const float* wrp = wt + (size_t)sidxS[w][jj] * M_;
        acc0 = fmaf(v, wrp[lane], acc0);
        acc1 = fmaf(v, wrp[lane + 64], acc1);
    }
    khat[(size_t)row * M_ + lane]      = acc0;
    khat[(size_t)row * M_ + lane + 64] = acc1;
    float r0 = acc0 - kinS[w][lane];
    float r1 = acc1 - kinS[w][lane + 64];
    float s = r0 * r0 + r1 * r1;
    #pragma unroll
    for (int o = 32; o > 0; o >>= 1) s += __shfl_xor(s, o, 64);
    if (lane == 0) partial[row] = s;
}

// ---------------------------------------------------------------------------
// K3a: finish_high (in-y keys): zero the key quarter + scatter its winners.
// Block 2048 does the loss reduce.
// ---------------------------------------------------------------------------
__global__ __launch_bounds__(256) void finish_high(float* __restrict__ y,
                                                   const int* __restrict__ cidx,
                                                   const float* __restrict__ cval,
                                                   const float* __restrict__ partial,
                                                   float* __restrict__ out_loss) {
    const int bid = blockIdx.x;                 // 2049 blocks
    const int tid = threadIdx.x;
    if (bid == 2048) {
        __shared__ float red[256];
        float s = 0.0f;
        for (int i = tid; i < ROWS / 4; i += 256) {
            float4 v = reinterpret_cast<const float4*>(partial)[i];
            s += v.x + v.y + v.z + v.w;
        }
        red[tid] = s;
        __syncthreads();
        for (int off = 128; off > 0; off >>= 1) {
            if (tid < off) red[tid] += red[tid + off];
            __syncthreads();
        }
        if (tid == 0) out_loss[0] = red[0] / (float)((size_t)B_ * L_ * M_);
        return;
    }
    const int row0 = bid * 16;
    const float4 z = {0.f, 0.f, 0.f, 0.f};
    #pragma unroll
    for (int i = 0; i < 16; ++i) {
        int g = i * 256 + tid;                  // 0..4095 over 16 rows x 256 f4
        int r = row0 + (g >> 8);
        int slot = g & 255;
        reinterpret_cast<float4*>(y + (size_t)r * N_ + 2048)[slot] = z;
    }
    __syncthreads();    // vmcnt(0) drain before barrier
    #pragma unroll
    for (int i = 0; i < 2; ++i) {
        int e = i * 256 + tid;                  // 0..511 winner entries
        int g = row0 * S_ + e;
        int n = cidx[g];
        if (n >= 2048 && n < 3072) {
            int r = row0 + (e >> 5);
            y[(size_t)r * N_ + n] = cval[g];
        }
    }
}

// K3b: loss-only tail (in-ws keys path)
__global__ __launch_bounds__(256) void reduce_loss(const float* __restrict__ partial,
                                                   float* __restrict__ out_loss) {
    __shared__ float red[256];
    int tid = threadIdx.x;
    float s = 0.0f;
    for (int i = tid; i < ROWS / 4; i += 256) {
        float4 v = reinterpret_cast<const float4*>(partial)[i];
        s += v.x + v.y + v.z + v.w;
    }
    red[tid] = s;
    __syncthreads();
    for (int off = 128; off > 0; off >>= 1) {
        if (tid < off) red[tid] += red[tid + off];
        __syncthreads();
    }
    if (tid == 0) out_loss[0] = red[0] / (float)((size_t)B_ * L_ * M_);
}

// ---------------------------------------------------------------------------
extern "C" void kernel_launch(void* const* d_in, const int* in_sizes, int n_in,
                              void* d_out, int out_size, void* d_ws, size_t ws_size,
                              hipStream_t stream) {
    const float* kin = (const float*)d_in[0];   // [B][L][M]
    const float* We  = (const float*)d_in[1];   // [L][N][M]
    // d_in[2] = b_e (unused by reference encode())
    const float* Wd  = (const float*)d_in[3];   // [L][M][N]
    const float* bd  = (const float*)d_in[4];   // [L][M]
    // d_in[5] = s (==32, hardcoded)

    float* out   = (float*)d_out;
    float* loss  = out;                                   // [1]
    float* khat  = out + 1;                               // [B*L*M]
    float* y_out = out + 1 + (size_t)B_ * L_ * M_;        // [B*L*N]

    char* ws = (char*)d_ws;
    const bool wsHuge = ws_size >= ((size_t)241u << 20);  // keys live in ws
    const bool wsBig  = ws_size >= ((size_t)113u << 20);  // transpose in prologue

    unsigned short* Wbf;
    unsigned short* Abf;
    int*   cidx;
    float* cval;
    float* cvec;
    float* partial;
    float* WdT;
    unsigned char* keys;
    int kstride, koff, loQ, hiQ;

    if (wsBig) {
        Wbf     = (unsigned short*)ws;                       // 0   .. 32 MiB
        Abf     = (unsigned short*)(ws + (32u << 20));       // 32  .. 40 MiB
        cidx    = (int*)  (ws + (40u << 20));                // 40  .. 44 MiB
        cval    = (float*)(ws + (44u << 20));                // 44  .. 48 MiB
        cvec    = (float*)(ws + (48u << 20));                // 48  .. 48.5 MiB
        partial = (float*)(ws + (48u << 20) + (512u << 10)); // 48.5.. 49 MiB
        WdT     = (float*)(ws + (49u << 20));                // 49  .. 113 MiB
    } else {
        Wbf     = (unsigned short*)ws;                       // 32 MiB
        Abf     = (unsigned short*)(ws + (64u << 20));       // 8 MiB
        cidx    = (int*)  (ws + (72u << 20));                // 4 MiB
        cval    = (float*)(ws + (76u << 20));                // 4 MiB
        cvec    = (float*)(ws + (80u << 20));                // 512 KiB
        partial = (float*)(ws + (81u << 20));                // 128 KiB
        WdT     = (float*)ws;                                // aliases Wbf
    }
    if (wsHuge) {
        keys = (unsigned char*)(ws + ((size_t)113u << 20));  // 113 .. 241 MiB
        kstride = 4096; koff = 0;
        loQ = 0; hiQ = 0;          // scatter ALL winners (y fully pre-zeroed)
    } else {
        keys = (unsigned char*)y_out;                        // keys inside y
        kstride = 16384; koff = 8192;
        loQ = 2048; hiQ = 3072;    // key quarter deferred to finish_high
    }

    int nblocks = 26624 + (wsBig ? 16384 : 0);
    prologue<<<nblocks, 256, 0, stream>>>(y_out, We, bd, Wbf, cvec, kin, Abf,
                                          Wd, WdT, wsHuge ? 1 : 0);
    // encoder: 1-D grid, chunked XCD swizzle; emits 8-bit keys
    encoder_mfma<<<8192, 256, 0, stream>>>(Abf, Wbf, cvec, keys, kstride, koff);
    if (!wsBig)
        transpose_wd<<<dim3(N_ / 32, M_ / 32, L_), 256, 0, stream>>>(Wd, WdT);
    // selector+decoder: XCD-chunked dispatch for We/WdT L2 residency
    topk_decode<<<ROWS / 4, 256, 0, stream>>>(y_out, keys, kstride, koff, loQ, hiQ,
                                              We, WdT, kin, cvec,
                                              cidx, cval, khat, partial);
    if (wsHuge) {
        reduce_loss<<<1, 256, 0, stream>>>(partial, loss);
    } else {
        finish_high<<<2049, 256, 0, stream>>>(y_out, cidx, cval, partial, loss);
    }
}